// Round 2
// baseline (1455.408 us; speedup 1.0000x reference)
//
#include <hip/hip_runtime.h>
#include <hip/hip_bf16.h>

// WordSentAtt: qf = relu(Q@W^T + b); S = qf@K^T (masked); attn = softmax; O = attn@K
// B=32, Lq=Lk=D=1024, f32 in/out. Split-bf16 (hi/lo) MFMA for qf and S.
// Tier A (ws>=340MB): pre-convert K(hi,lo,hiT),Q(hi,lo),W(hi,lo) once into ws;
//   all GEMMs use global_load_lds bf16 staging (no per-block cvt). qf stored
//   packed [hi(1024 u16)|lo(1024 u16)] per row in d_out; attn bf16 overwrites
//   the lo half after use; k_pv (2 launches, d-halves) writes final f32 O.
// Tier B2 (ws>=202MB): K planes only; qf kernel keeps in-kernel cvt (packed out).
// Tier C: round-1 fallback, no ws.

typedef __attribute__((ext_vector_type(4))) float f32x4;
typedef __attribute__((ext_vector_type(8))) short s16x8;

#define MFMA16(a, b, c) __builtin_amdgcn_mfma_f32_16x16x32_bf16((a), (b), (c), 0, 0, 0)

__device__ __forceinline__ unsigned short f2bf(float x) {
  unsigned u = __builtin_bit_cast(unsigned, x);
  return (unsigned short)((u + 0x7FFFu + ((u >> 16) & 1u)) >> 16);
}
__device__ __forceinline__ float bf2f(unsigned short h) {
  return __builtin_bit_cast(float, ((unsigned)h) << 16);
}
// XOR swizzle (round-1 style) for reg-staged tiles
__device__ __forceinline__ int swz(int row, int col) {
  return (row * 64 + col) ^ ((row & 7) << 3);
}
__device__ __forceinline__ void cvt8(const float* __restrict__ s, s16x8& h8, s16x8& l8) {
  f32x4 a = *(const f32x4*)s;
  f32x4 b = *(const f32x4*)(s + 4);
#pragma unroll
  for (int i = 0; i < 8; i++) {
    float v = (i < 4) ? a[i] : b[i - 4];
    unsigned short hu = f2bf(v);
    unsigned short lu = f2bf(v - bf2f(hu));
    h8[i] = (short)hu;
    l8[i] = (short)lu;
  }
}
// async global->LDS, 16B per lane; lds base must be wave-uniform.
__device__ __forceinline__ void gld16(const void* g, void* lds) {
  __builtin_amdgcn_global_load_lds((const __attribute__((address_space(1))) unsigned int*)g,
                                   (__attribute__((address_space(3))) unsigned int*)lds, 16, 0, 0);
}

// ws layout (bytes)
#define OFF_KHI 0ULL
#define OFF_KLO 67108864ULL
#define OFF_KHIT 134217728ULL
#define OFF_QHI 201326592ULL
#define OFF_QLO 268435456ULL
#define OFF_WHI 335544320ULL
#define OFF_WLO 337641472ULL
#define WS_TIER_A 339738624ULL
#define WS_TIER_B2 201326592ULL

// ================= Tier A pre-convert kernels =================
__global__ __launch_bounds__(256) void k_cvt_pair(const float* __restrict__ src,
                                                  unsigned short* __restrict__ hi,
                                                  unsigned short* __restrict__ lo, int n8) {
  int i = blockIdx.x * 256 + threadIdx.x;
  if (i >= n8) return;
  s16x8 h, l;
  cvt8(src + (size_t)i * 8, h, l);
  *(s16x8*)(hi + (size_t)i * 8) = h;
  *(s16x8*)(lo + (size_t)i * 8) = l;
}

// K[b][k][d] f32 -> Khi/Klo [b][k][d] u16 + KhiT [b][d][k] u16 (LDS transpose)
__global__ __launch_bounds__(256) void k_cvt_k(const float* __restrict__ K,
                                               unsigned short* __restrict__ Khi,
                                               unsigned short* __restrict__ Klo,
                                               unsigned short* __restrict__ KhiT) {
  __shared__ unsigned T[64 * 65];
  const int t = threadIdx.x;
  const int db0 = blockIdx.x * 64, kb0 = blockIdx.y * 64, b = blockIdx.z;
  const size_t base = (size_t)b * 1024 * 1024;
#pragma unroll
  for (int i = 0; i < 2; i++) {
    const int r = (t >> 3) + i * 32, c0 = (t & 7) * 8;
    s16x8 h, l;
    cvt8(K + base + (size_t)(kb0 + r) * 1024 + db0 + c0, h, l);
    *(s16x8*)(Khi + base + (size_t)(kb0 + r) * 1024 + db0 + c0) = h;
    *(s16x8*)(Klo + base + (size_t)(kb0 + r) * 1024 + db0 + c0) = l;
#pragma unroll
    for (int j = 0; j < 8; j++)
      T[r * 65 + c0 + j] = ((unsigned)(unsigned short)h[j] << 16) | (unsigned short)l[j];
  }
  __syncthreads();
#pragma unroll
  for (int i = 0; i < 2; i++) {
    const int rd = (t >> 3) + i * 32, ck0 = (t & 7) * 8;
    s16x8 h;
#pragma unroll
    for (int j = 0; j < 8; j++) h[j] = (short)(unsigned short)(T[(ck0 + j) * 65 + rd] >> 16);
    *(s16x8*)(KhiT + base + (size_t)(db0 + rd) * 1024 + kb0 + ck0) = h;
  }
}

// ================= Tier A: qf GEMM (all operands pre-converted) =================
// grid flat 2048 blocks (bx 256 x by 8), 256 thr = 4 waves (2x2). 128x128 tile, BK=64.
// Output: packed rows in d_out: u16[row][0..1024)=hi, [1024..2048)=lo.
__global__ __launch_bounds__(256, 2) void k_qf2(const unsigned short* __restrict__ Qhi,
                                                const unsigned short* __restrict__ Qlo,
                                                const unsigned short* __restrict__ Whi,
                                                const unsigned short* __restrict__ Wlo,
                                                const float* __restrict__ bias,
                                                float* __restrict__ outp) {
  __shared__ __align__(16) unsigned short Ah[128 * 64], Al[128 * 64], Bh[128 * 64], Bl[128 * 64];
  const int t = threadIdx.x;
  // XCD swizzle: dispatch-linear i -> xcd = i&7; pin by (W tile) per XCD
  const int i = blockIdx.y * 256 + blockIdx.x;  // hmm grid (256,8): linear = bx + by*256
  const int by = i & 7, bx = i >> 3;
  const int m0 = bx * 128, n0 = by * 128;
  const int w = t >> 6, l = t & 63, wm = w >> 1, wn = w & 1, g = l >> 4, ln = l & 15;
  const int lrow = l >> 3, lc8 = (l & 7) * 8;
  const f32x4 fz = {0.f, 0.f, 0.f, 0.f};
  f32x4 acc[4][4];
#pragma unroll
  for (int a = 0; a < 4; a++)
#pragma unroll
    for (int bq = 0; bq < 4; bq++) acc[a][bq] = fz;
#pragma unroll 1
  for (int k0 = 0; k0 < 1024; k0 += 64) {
#pragma unroll
    for (int j = 0; j < 4; j++) {
      const int ch = w * 4 + j;
      const int row = ch * 8 + lrow;
      const int sc = lc8 ^ (lrow << 3);  // source pre-swizzle (T2, rule 21)
      gld16(Qhi + (size_t)(m0 + row) * 1024 + k0 + sc, &Ah[ch * 512]);
      gld16(Qlo + (size_t)(m0 + row) * 1024 + k0 + sc, &Al[ch * 512]);
      gld16(Whi + (size_t)(n0 + row) * 1024 + k0 + sc, &Bh[ch * 512]);
      gld16(Wlo + (size_t)(n0 + row) * 1024 + k0 + sc, &Bl[ch * 512]);
    }
    __syncthreads();
#pragma unroll
    for (int ks = 0; ks < 2; ks++) {
      const int kc = ks * 32 + g * 8;
      s16x8 ah[4], al[4], bh[4], bl[4];
#pragma unroll
      for (int mf = 0; mf < 4; mf++) {
        const int row = wm * 64 + mf * 16 + ln;
        const int idx = row * 64 + (kc ^ ((row & 7) << 3));
        ah[mf] = *(const s16x8*)&Ah[idx];
        al[mf] = *(const s16x8*)&Al[idx];
      }
#pragma unroll
      for (int nf = 0; nf < 4; nf++) {
        const int row = wn * 64 + nf * 16 + ln;
        const int idx = row * 64 + (kc ^ ((row & 7) << 3));
        bh[nf] = *(const s16x8*)&Bh[idx];
        bl[nf] = *(const s16x8*)&Bl[idx];
      }
#pragma unroll
      for (int mf = 0; mf < 4; mf++)
#pragma unroll
        for (int nf = 0; nf < 4; nf++) {
          acc[mf][nf] = MFMA16(ah[mf], bh[nf], acc[mf][nf]);
          acc[mf][nf] = MFMA16(ah[mf], bl[nf], acc[mf][nf]);
          acc[mf][nf] = MFMA16(al[mf], bh[nf], acc[mf][nf]);
        }
    }
    __syncthreads();
  }
  unsigned short* oc = (unsigned short*)outp;
#pragma unroll
  for (int nf = 0; nf < 4; nf++) {
    const int col = n0 + wn * 64 + nf * 16 + ln;
    const float bv = bias[col];
#pragma unroll
    for (int mf = 0; mf < 4; mf++)
#pragma unroll
      for (int r = 0; r < 4; r++) {
        const int row = m0 + wm * 64 + mf * 16 + g * 4 + r;
        float v = acc[mf][nf][r] + bv;
        v = v > 0.f ? v : 0.f;
        unsigned short h = f2bf(v);
        oc[(size_t)row * 2048 + col] = h;
        oc[(size_t)row * 2048 + 1024 + col] = f2bf(v - bf2f(h));
      }
  }
}

// ================= Tier A: score GEMM + masked softmax =================
// grid flat 512 (qt 16 x b 32), 512 thr = 8 waves (2 wm x 4 wn). S[64][1024] in regs.
__global__ __launch_bounds__(512, 2) void k_attn2(const unsigned short* __restrict__ Khi,
                                                  const unsigned short* __restrict__ Klo,
                                                  const float* __restrict__ mask,
                                                  float* __restrict__ dout) {
  __shared__ __align__(16) unsigned short qh[64 * 64], ql[64 * 64], kh[128 * 64], kl[128 * 64];
  __shared__ float mask_s[1024];
  __shared__ float red[4][64];
  const int t = threadIdx.x;
  // XCD swizzle: xcd = i&7 owns b in {4*xcd..4*xcd+3}
  const int i = blockIdx.y * 16 + blockIdx.x;
  const int x = i & 7, jj = i >> 3;
  const int b = x * 4 + (jj >> 4), qt = jj & 15;
  const int q0 = qt * 64;
  const int w = t >> 6, l = t & 63, wm = w >> 2, wn = w & 3, g = l >> 4, ln = l & 15;
  const int lrow = l >> 3, lc8 = (l & 7) * 8, sc = lc8 ^ (lrow << 3);
  for (int ii = t; ii < 1024; ii += 512) mask_s[ii] = mask[b * 1024 + ii];
  const f32x4 fz = {0.f, 0.f, 0.f, 0.f};
  f32x4 acc[8][2][2];
#pragma unroll
  for (int kt = 0; kt < 8; kt++)
#pragma unroll
    for (int mf = 0; mf < 2; mf++)
#pragma unroll
      for (int nf = 0; nf < 2; nf++) acc[kt][mf][nf] = fz;
  const unsigned short* dou16 = (const unsigned short*)dout;
  const size_t kbase = (size_t)b * 1024 * 1024;
#pragma unroll 1
  for (int dc = 0; dc < 16; dc++) {
    {  // stage q planes (64x64): 8 chunks, 1/wave/plane
      const int row = w * 8 + lrow;
      const unsigned short* gq = dou16 + (size_t)(b * 1024 + q0 + row) * 2048 + dc * 64 + sc;
      gld16(gq, &qh[w * 512]);
      gld16(gq + 1024, &ql[w * 512]);
    }
#pragma unroll 1
    for (int kt = 0; kt < 8; kt++) {
#pragma unroll
      for (int j = 0; j < 2; j++) {  // stage k planes (128x64): 16 chunks, 2/wave/plane
        const int ch = w * 2 + j;
        const int row = ch * 8 + lrow;
        const size_t go = kbase + (size_t)(kt * 128 + row) * 1024 + dc * 64 + sc;
        gld16(Khi + go, &kh[ch * 512]);
        gld16(Klo + go, &kl[ch * 512]);
      }
      __syncthreads();
#pragma unroll
      for (int ks = 0; ks < 2; ks++) {
        const int kc = ks * 32 + g * 8;
        s16x8 ah[2], al2[2], bh[2], bl[2];
#pragma unroll
        for (int mf = 0; mf < 2; mf++) {
          const int row = wm * 32 + mf * 16 + ln;
          const int idx = row * 64 + (kc ^ ((row & 7) << 3));
          ah[mf] = *(const s16x8*)&qh[idx];
          al2[mf] = *(const s16x8*)&ql[idx];
        }
#pragma unroll
        for (int nf = 0; nf < 2; nf++) {
          const int row = wn * 32 + nf * 16 + ln;
          const int idx = row * 64 + (kc ^ ((row & 7) << 3));
          bh[nf] = *(const s16x8*)&kh[idx];
          bl[nf] = *(const s16x8*)&kl[idx];
        }
#pragma unroll
        for (int mf = 0; mf < 2; mf++)
#pragma unroll
          for (int nf = 0; nf < 2; nf++) {
            acc[kt][mf][nf] = MFMA16(ah[mf], bh[nf], acc[kt][mf][nf]);
            acc[kt][mf][nf] = MFMA16(ah[mf], bl[nf], acc[kt][mf][nf]);
            acc[kt][mf][nf] = MFMA16(al2[mf], bh[nf], acc[kt][mf][nf]);
          }
      }
      __syncthreads();
    }
  }
  // ---- masked softmax (identical math to round-1) ----
  float rmax[2][4];
#pragma unroll
  for (int mf = 0; mf < 2; mf++)
#pragma unroll
    for (int r = 0; r < 4; r++) rmax[mf][r] = -1e30f;
#pragma unroll
  for (int kt = 0; kt < 8; kt++)
#pragma unroll
    for (int nf = 0; nf < 2; nf++) {
      const int k = kt * 128 + wn * 32 + nf * 16 + ln;
      const bool mk = mask_s[k] != 0.f;
#pragma unroll
      for (int mf = 0; mf < 2; mf++)
#pragma unroll
        for (int r = 0; r < 4; r++)
          if (mk) rmax[mf][r] = fmaxf(rmax[mf][r], acc[kt][mf][nf][r]);
    }
#pragma unroll
  for (int off = 1; off < 16; off <<= 1)
#pragma unroll
    for (int mf = 0; mf < 2; mf++)
#pragma unroll
      for (int r = 0; r < 4; r++) rmax[mf][r] = fmaxf(rmax[mf][r], __shfl_xor(rmax[mf][r], off));
  if (ln == 0) {
#pragma unroll
    for (int mf = 0; mf < 2; mf++)
#pragma unroll
      for (int r = 0; r < 4; r++) red[wn][wm * 32 + mf * 16 + g * 4 + r] = rmax[mf][r];
  }
  __syncthreads();
#pragma unroll
  for (int mf = 0; mf < 2; mf++)
#pragma unroll
    for (int r = 0; r < 4; r++) {
      const int row = wm * 32 + mf * 16 + g * 4 + r;
      rmax[mf][r] = fmaxf(fmaxf(red[0][row], red[1][row]), fmaxf(red[2][row], red[3][row]));
    }
  __syncthreads();
  float rsum[2][4];
#pragma unroll
  for (int mf = 0; mf < 2; mf++)
#pragma unroll
    for (int r = 0; r < 4; r++) rsum[mf][r] = 0.f;
#pragma unroll
  for (int kt = 0; kt < 8; kt++)
#pragma unroll
    for (int nf = 0; nf < 2; nf++) {
      const int k = kt * 128 + wn * 32 + nf * 16 + ln;
      const bool mk = mask_s[k] != 0.f;
#pragma unroll
      for (int mf = 0; mf < 2; mf++)
#pragma unroll
        for (int r = 0; r < 4; r++)
          if (mk) rsum[mf][r] += __expf(acc[kt][mf][nf][r] - rmax[mf][r]);
    }
#pragma unroll
  for (int off = 1; off < 16; off <<= 1)
#pragma unroll
    for (int mf = 0; mf < 2; mf++)
#pragma unroll
      for (int r = 0; r < 4; r++) rsum[mf][r] += __shfl_xor(rsum[mf][r], off);
  if (ln == 0) {
#pragma unroll
    for (int mf = 0; mf < 2; mf++)
#pragma unroll
      for (int r = 0; r < 4; r++) red[wn][wm * 32 + mf * 16 + g * 4 + r] = rsum[mf][r];
  }
  __syncthreads();
  float rinv[2][4];
#pragma unroll
  for (int mf = 0; mf < 2; mf++)
#pragma unroll
    for (int r = 0; r < 4; r++) {
      const int row = wm * 32 + mf * 16 + g * 4 + r;
      rinv[mf][r] = 1.f / (red[0][row] + red[1][row] + red[2][row] + red[3][row]);
    }
  // attn bf16 -> lo half of this block's own rows (qlo fully consumed)
  unsigned short* oc = (unsigned short*)dout;
#pragma unroll
  for (int kt = 0; kt < 8; kt++)
#pragma unroll
    for (int nf = 0; nf < 2; nf++) {
      const int k = kt * 128 + wn * 32 + nf * 16 + ln;
      const bool mk = mask_s[k] != 0.f;
#pragma unroll
      for (int mf = 0; mf < 2; mf++)
#pragma unroll
        for (int r = 0; r < 4; r++) {
          const int q = q0 + wm * 32 + mf * 16 + g * 4 + r;
          float p = mk ? __expf(acc[kt][mf][nf][r] - rmax[mf][r]) * rinv[mf][r] : 0.f;
          oc[(size_t)(b * 1024 + q) * 2048 + 1024 + k] = f2bf(p);
        }
    }
}

// ================= Tier A: O = attn @ K via KhiT =================
// grid flat 256 (qt 8 x b 32), 512 thr = 8 waves (2 wm x 4 wd). 128q x 512d, BK=64.
__global__ __launch_bounds__(512, 2) void k_pv2(const unsigned short* __restrict__ KhiT,
                                                float* __restrict__ dout, const int dh) {
  __shared__ __align__(16) unsigned short P[128 * 64];
  __shared__ __align__(16) unsigned short KT[512 * 64];
  const int t = threadIdx.x;
  const int i = blockIdx.y * 8 + blockIdx.x;
  const int x = i & 7, jj = i >> 3;
  const int b = x * 4 + (jj >> 3), qt = jj & 7;
  const int q0 = qt * 128, d0 = dh * 512;
  const int w = t >> 6, l = t & 63, wm = w >> 2, wd = w & 3, g = l >> 4, ln = l & 15;
  const int lrow = l >> 3, lc8 = (l & 7) * 8, sc = lc8 ^ (lrow << 3);
  const f32x4 fz = {0.f, 0.f, 0.f, 0.f};
  f32x4 acc[4][8];
#pragma unroll
  for (int a = 0; a < 4; a++)
#pragma unroll
    for (int bq = 0; bq < 8; bq++) acc[a][bq] = fz;
  const unsigned short* dou16 = (const unsigned short*)dout;
  const size_t kbase = (size_t)b * 1024 * 1024;
#pragma unroll 1
  for (int k0 = 0; k0 < 1024; k0 += 64) {
#pragma unroll
    for (int j = 0; j < 2; j++) {  // P: 16 chunks
      const int ch = w * 2 + j;
      const int row = ch * 8 + lrow;
      gld16(dou16 + (size_t)(b * 1024 + q0 + row) * 2048 + 1024 + k0 + sc, &P[ch * 512]);
    }
#pragma unroll
    for (int j = 0; j < 8; j++) {  // KT: 64 chunks
      const int ch = w * 8 + j;
      const int row = ch * 8 + lrow;
      gld16(KhiT + kbase + (size_t)(d0 + row) * 1024 + k0 + sc, &KT[ch * 512]);
    }
    __syncthreads();
#pragma unroll
    for (int ks = 0; ks < 2; ks++) {
      const int kc = ks * 32 + g * 8;
      s16x8 a[4], bb[8];
#pragma unroll
      for (int mf = 0; mf < 4; mf++) {
        const int row = wm * 64 + mf * 16 + ln;
        a[mf] = *(const s16x8*)&P[row * 64 + (kc ^ ((row & 7) << 3))];
      }
#pragma unroll
      for (int nf = 0; nf < 8; nf++) {
        const int row = wd * 128 + nf * 16 + ln;
        bb[nf] = *(const s16x8*)&KT[row * 64 + (kc ^ ((row & 7) << 3))];
      }
#pragma unroll
      for (int mf = 0; mf < 4; mf++)
#pragma unroll
        for (int nf = 0; nf < 8; nf++) acc[mf][nf] = MFMA16(a[mf], bb[nf], acc[mf][nf]);
    }
    __syncthreads();
  }
#pragma unroll
  for (int mf = 0; mf < 4; mf++)
#pragma unroll
    for (int nf = 0; nf < 8; nf++)
#pragma unroll
      for (int r = 0; r < 4; r++) {
        const int q = q0 + wm * 64 + mf * 16 + g * 4 + r;
        const int d = d0 + wd * 128 + nf * 16 + ln;
        dout[(size_t)(b * 1024 + q) * 1024 + d] = acc[mf][nf][r];
      }
}

// ================= Tier B/C: round-1 kernels (fallback) =================
// k_qf: packout=1 writes packed hi/lo u16 rows; packout=0 writes f32.
__global__ __launch_bounds__(256, 2) void k_qf(const float* __restrict__ Q,
                                               const float* __restrict__ W,
                                               const float* __restrict__ bias,
                                               float* __restrict__ qf, const int packout) {
  __shared__ __align__(16) short Ah[128 * 64], Al[128 * 64], Bh[128 * 64], Bl[128 * 64];
  const int t = threadIdx.x;
  const int m0 = blockIdx.x * 128, n0 = blockIdx.y * 128;
  const int w = t >> 6, l = t & 63, wm = w >> 1, wn = w & 1, g = l >> 4, ln = l & 15;
  const f32x4 fz = {0.f, 0.f, 0.f, 0.f};
  f32x4 acc[4][4];
#pragma unroll
  for (int a = 0; a < 4; a++)
#pragma unroll
    for (int bq = 0; bq < 4; bq++) acc[a][bq] = fz;
  const int srow = t >> 1, scol = (t & 1) * 32;
#pragma unroll 1
  for (int k0 = 0; k0 < 1024; k0 += 64) {
    const float* sa = Q + (size_t)(m0 + srow) * 1024 + k0 + scol;
    const float* sb = W + (size_t)(n0 + srow) * 1024 + k0 + scol;
#pragma unroll
    for (int c = 0; c < 32; c += 8) {
      s16x8 h, lo;
      cvt8(sa + c, h, lo);
      int si = swz(srow, scol + c);
      *(s16x8*)&Ah[si] = h;
      *(s16x8*)&Al[si] = lo;
    }
#pragma unroll
    for (int c = 0; c < 32; c += 8) {
      s16x8 h, lo;
      cvt8(sb + c, h, lo);
      int si = swz(srow, scol + c);
      *(s16x8*)&Bh[si] = h;
      *(s16x8*)&Bl[si] = lo;
    }
    __syncthreads();
#pragma unroll
    for (int ks = 0; ks < 2; ks++) {
      const int kc = ks * 32 + g * 8;
      s16x8 ah[4], al[4], bh[4], bl[4];
#pragma unroll
      for (int mf = 0; mf < 4; mf++) {
        int si = swz(wm * 64 + mf * 16 + ln, kc);
        ah[mf] = *(s16x8*)&Ah[si];
        al[mf] = *(s16x8*)&Al[si];
      }
#pragma unroll
      for (int nf = 0; nf < 4; nf++) {
        int si = swz(wn * 64 + nf * 16 + ln, kc);
        bh[nf] = *(s16x8*)&Bh[si];
        bl[nf] = *(s16x8*)&Bl[si];
      }
#pragma unroll
      for (int mf = 0; mf < 4; mf++)
#pragma unroll
        for (int nf = 0; nf < 4; nf++) {
          acc[mf][nf] = MFMA16(ah[mf], bh[nf], acc[mf][nf]);
          acc[mf][nf] = MFMA16(ah[mf], bl[nf], acc[mf][nf]);
          acc[mf][nf] = MFMA16(al[mf], bh[nf], acc[mf][nf]);
        }
    }
    __syncthreads();
  }
  unsigned short* oc = (unsigned short*)qf;
#pragma unroll
  for (int nf = 0; nf < 4; nf++) {
    const int col = n0 + wn * 64 + nf * 16 + ln;
    const float bv = bias[col];
#pragma unroll
    for (int mf = 0; mf < 4; mf++)
#pragma unroll
      for (int r = 0; r < 4; r++) {
        const int row = m0 + wm * 64 + mf * 16 + g * 4 + r;
        float v = acc[mf][nf][r] + bv;
        v = v > 0.f ? v : 0.f;
        if (packout) {
          unsigned short h = f2bf(v);
          oc[(size_t)row * 2048 + col] = h;
          oc[(size_t)row * 2048 + 1024 + col] = f2bf(v - bf2f(h));
        } else {
          qf[(size_t)row * 1024 + col] = v;
        }
      }
  }
}

__global__ __launch_bounds__(512, 2) void k_attn(const float* __restrict__ Key,
                                                 const float* __restrict__ mask,
                                                 float* __restrict__ dout) {
  __shared__ __align__(16) short qh[64 * 64], qlo[64 * 64], kh[128 * 64], klo[128 * 64];
  __shared__ float mask_s[1024];
  __shared__ float red[4][64];
  const int t = threadIdx.x;
  const int qt = blockIdx.x, b = blockIdx.y;
  const int q0 = qt * 64;
  const int w = t >> 6, l = t & 63, wm = w >> 2, wn = w & 3, g = l >> 4, ln = l & 15;
  for (int i = t; i < 1024; i += 512) mask_s[i] = mask[b * 1024 + i];
  const f32x4 fz = {0.f, 0.f, 0.f, 0.f};
  f32x4 acc[8][2][2];
#pragma unroll
  for (int kt = 0; kt < 8; kt++)
#pragma unroll
    for (int mf = 0; mf < 2; mf++)
#pragma unroll
      for (int nf = 0; nf < 2; nf++) acc[kt][mf][nf] = fz;
  const float* qfb = dout + (size_t)(b * 1024 + q0) * 1024;
  const float* kb = Key + (size_t)b * 1024 * 1024;
  const int qrow = t >> 3, qcol = (t & 7) * 8;
  const int krow = t >> 2, kcol0 = (t & 3) * 16;
#pragma unroll 1
  for (int dc = 0; dc < 16; dc++) {
    {
      s16x8 h, lo;
      cvt8(qfb + (size_t)qrow * 1024 + dc * 64 + qcol, h, lo);
      int si = swz(qrow, qcol);
      *(s16x8*)&qh[si] = h;
      *(s16x8*)&qlo[si] = lo;
    }
#pragma unroll
    for (int kt = 0; kt < 8; kt++) {
      {
        const float* s = kb + (size_t)(kt * 128 + krow) * 1024 + dc * 64 + kcol0;
        s16x8 h, lo;
        cvt8(s, h, lo);
        int si = swz(krow, kcol0);
        *(s16x8*)&kh[si] = h;
        *(s16x8*)&klo[si] = lo;
        cvt8(s + 8, h, lo);
        si = swz(krow, kcol0 + 8);
        *(s16x8*)&kh[si] = h;
        *(s16x8*)&klo[si] = lo;
      }
      __syncthreads();
#pragma unroll
      for (int ks = 0; ks < 2; ks++) {
        const int kc = ks * 32 + g * 8;
        s16x8 ah[2], al2[2], bh[2], bl[2];
#pragma unroll
        for (int mf = 0; mf < 2; mf++) {
          int si = swz(wm * 32 + mf * 16 + ln, kc);
          ah[mf] = *(s16x8*)&qh[si];
          al2[mf] = *(s16x8*)&qlo[si];
        }
#pragma unroll
        for (int nf = 0; nf < 2; nf++) {
          int si = swz(wn * 32 + nf * 16 + ln, kc);
          bh[nf] = *(s16x8*)&kh[si];
          bl[nf] = *(s16x8*)&klo[si];
        }
#pragma unroll
        for (int mf = 0; mf < 2; mf++)
#pragma unroll
          for (int nf = 0; nf < 2; nf++) {
            acc[kt][mf][nf] = MFMA16(ah[mf], bh[nf], acc[kt][mf][nf]);
            acc[kt][mf][nf] = MFMA16(ah[mf], bl[nf], acc[kt][mf][nf]);
            acc[kt][mf][nf] = MFMA16(al2[mf], bh[nf], acc[kt][mf][nf]);
          }
      }
      __syncthreads();
    }
  }
  float rmax[2][4];
#pragma unroll
  for (int mf = 0; mf < 2; mf++)
#pragma unroll
    for (int r = 0; r < 4; r++) rmax[mf][r] = -1e30f;
#pragma unroll
  for (int kt = 0; kt < 8; kt++)
#pragma unroll
    for (int nf = 0; nf < 2; nf++) {
      const int k = kt * 128 + wn * 32 + nf * 16 + ln;
      const bool mk = mask_s[k] != 0.f;
#pragma unroll
      for (int mf = 0; mf < 2; mf++)
#pragma unroll
        for (int r = 0; r < 4; r++)
          if (mk) rmax[mf][r] = fmaxf(rmax[mf][r], acc[kt][mf][nf][r]);
    }
#pragma unroll
  for (int off = 1; off < 16; off <<= 1)
#pragma unroll
    for (int mf = 0; mf < 2; mf++)
#pragma unroll
      for (int r = 0; r < 4; r++) rmax[mf][r] = fmaxf(rmax[mf][r], __shfl_xor(rmax[mf][r], off));
  if (ln == 0) {
#pragma unroll
    for (int mf = 0; mf < 2; mf++)
#pragma unroll
      for (int r = 0; r < 4; r++) red[wn][wm * 32 + mf * 16 + g * 4 + r] = rmax[mf][r];
  }
  __syncthreads();
#pragma unroll
  for (int mf = 0; mf < 2; mf++)
#pragma unroll
    for (int r = 0; r < 4; r++) {
      const int row = wm * 32 + mf * 16 + g * 4 + r;
      rmax[mf][r] = fmaxf(fmaxf(red[0][row], red[1][row]), fmaxf(red[2][row], red[3][row]));
    }
  __syncthreads();
  float rsum[2][4];
#pragma unroll
  for (int mf = 0; mf < 2; mf++)
#pragma unroll
    for (int r = 0; r < 4; r++) rsum[mf][r] = 0.f;
#pragma unroll
  for (int kt = 0; kt < 8; kt++)
#pragma unroll
    for (int nf = 0; nf < 2; nf++) {
      const int k = kt * 128 + wn * 32 + nf * 16 + ln;
      const bool mk = mask_s[k] != 0.f;
#pragma unroll
      for (int mf = 0; mf < 2; mf++)
#pragma unroll
        for (int r = 0; r < 4; r++)
          if (mk) rsum[mf][r] += __expf(acc[kt][mf][nf][r] - rmax[mf][r]);
    }
#pragma unroll
  for (int off = 1; off < 16; off <<= 1)
#pragma unroll
    for (int mf = 0; mf < 2; mf++)
#pragma unroll
      for (int r = 0; r < 4; r++) rsum[mf][r] += __shfl_xor(rsum[mf][r], off);
  if (ln == 0) {
#pragma unroll
    for (int mf = 0; mf < 2; mf++)
#pragma unroll
      for (int r = 0; r < 4; r++) red[wn][wm * 32 + mf * 16 + g * 4 + r] = rsum[mf][r];
  }
  __syncthreads();
  float rinv[2][4];
#pragma unroll
  for (int mf = 0; mf < 2; mf++)
#pragma unroll
    for (int r = 0; r < 4; r++) {
      const int row = wm * 32 + mf * 16 + g * 4 + r;
      rinv[mf][r] = 1.f / (red[0][row] + red[1][row] + red[2][row] + red[3][row]);
    }
  char* oc = (char*)dout;
#pragma unroll
  for (int kt = 0; kt < 8; kt++)
#pragma unroll
    for (int nf = 0; nf < 2; nf++) {
      const int k = kt * 128 + wn * 32 + nf * 16 + ln;
      const bool mk = mask_s[k] != 0.f;
#pragma unroll
      for (int mf = 0; mf < 2; mf++)
#pragma unroll
        for (int r = 0; r < 4; r++) {
          const int q = q0 + wm * 32 + mf * 16 + g * 4 + r;
          float p = mk ? __expf(acc[kt][mf][nf][r] - rmax[mf][r]) * rinv[mf][r] : 0.f;
          *(unsigned short*)(oc + (size_t)(b * 1024 + q) * 4096 + 2048 + k * 2) = f2bf(p);
        }
    }
}

__global__ __launch_bounds__(512, 2) void k_pv(const float* __restrict__ Key,
                                               float* __restrict__ dout, const int dh) {
  __shared__ __align__(16) short P[128 * 64];
  __shared__ __align__(16) short KT[512 * 64];
  const int t = threadIdx.x;
  const int qt = blockIdx.x, b = blockIdx.y;
  const int q0 = qt * 128, d0 = dh * 512;
  const int w = t >> 6, l = t & 63, wm = w >> 2, wd = w & 3, g = l >> 4, ln = l & 15;
  const f32x4 fz = {0.f, 0.f, 0.f, 0.f};
  f32x4 acc[4][8];
#pragma unroll
  for (int a = 0; a < 4; a++)
#pragma unroll
    for (int bq = 0; bq < 8; bq++) acc[a][bq] = fz;
  const char* ab = (const char*)dout;
  const int prow = t >> 2, pc0 = (t & 3) * 16;
#pragma unroll 1
  for (int k0 = 0; k0 < 1024; k0 += 64) {
    {
      const unsigned short* s =
          (const unsigned short*)(ab + (size_t)(b * 1024 + q0 + prow) * 4096 + 2048) + k0 + pc0;
      s16x8 p0 = *(const s16x8*)s, p1 = *(const s16x8*)(s + 8);
      *(s16x8*)&P[swz(prow, pc0)] = p0;
      *(s16x8*)&P[swz(prow, pc0 + 8)] = p1;
    }
    {
      const float* ksrc = Key + (size_t)b * 1024 * 1024 + (size_t)k0 * 1024 + d0 + t;
#pragma unroll
      for (int kg = 0; kg < 8; kg++) {
        s16x8 h;
#pragma unroll
        for (int j = 0; j < 8; j++) h[j] = (short)f2bf(ksrc[(size_t)(kg * 8 + j) * 1024]);
        *(s16x8*)&KT[swz(t, kg * 8)] = h;
      }
    }
    __syncthreads();
#pragma unroll
    for (int ks = 0; ks < 2; ks++) {
      const int kc = ks * 32 + g * 8;
      s16x8 a[4], bb[8];
#pragma unroll
      for (int mf = 0; mf < 4; mf++) a[mf] = *(s16x8*)&P[swz(wm * 64 + mf * 16 + ln, kc)];
#pragma unroll
      for (int nf = 0; nf < 8; nf++) bb[nf] = *(s16x8*)&KT[swz(wd * 128 + nf * 16 + ln, kc)];
#pragma unroll
      for (int mf = 0; mf < 4; mf++)
#pragma unroll
        for (int nf = 0; nf < 8; nf++) acc[mf][nf] = MFMA16(a[mf], bb[nf], acc[mf][nf]);
    }
    __syncthreads();
  }
#pragma unroll
  for (int mf = 0; mf < 4; mf++)
#pragma unroll
    for (int nf = 0; nf < 8; nf++)
#pragma unroll
      for (int r = 0; r < 4; r++) {
        const int q = q0 + wm * 64 + mf * 16 + g * 4 + r;
        const int d = d0 + wd * 128 + nf * 16 + ln;
        dout[(size_t)(b * 1024 + q) * 1024 + d] = acc[mf][nf][r];
      }
}

extern "C" void kernel_launch(void* const* d_in, const int* in_sizes, int n_in,
                              void* d_out, int out_size, void* d_ws, size_t ws_size,
                              hipStream_t stream) {
  const float* Q = (const float*)d_in[0];
  const float* K = (const float*)d_in[1];
  const float* M = (const float*)d_in[2];
  const float* W = (const float*)d_in[3];
  const float* bias = (const float*)d_in[4];
  float* out = (float*)d_out;
  char* wsb = (char*)d_ws;
  (void)in_sizes; (void)n_in; (void)out_size;

  const bool tierA = ws_size >= WS_TIER_A;
  const bool tierB2 = !tierA && ws_size >= WS_TIER_B2;
  if (tierA || tierB2) {
    unsigned short* Khi = (unsigned short*)(wsb + OFF_KHI);
    unsigned short* Klo = (unsigned short*)(wsb + OFF_KLO);
    unsigned short* KhiT = (unsigned short*)(wsb + OFF_KHIT);
    k_cvt_k<<<dim3(16, 16, 32), 256, 0, stream>>>(K, Khi, Klo, KhiT);
    if (tierA) {
      unsigned short* Qhi = (unsigned short*)(wsb + OFF_QHI);
      unsigned short* Qlo = (unsigned short*)(wsb + OFF_QLO);
      unsigned short* Whi = (unsigned short*)(wsb + OFF_WHI);
      unsigned short* Wlo = (unsigned short*)(wsb + OFF_WLO);
      k_cvt_pair<<<16384, 256, 0, stream>>>(Q, Qhi, Qlo, 4194304);
      k_cvt_pair<<<512, 256, 0, stream>>>(W, Whi, Wlo, 131072);
      k_qf2<<<dim3(256, 8), 256, 0, stream>>>(Qhi, Qlo, Whi, Wlo, bias, out);
    } else {
      k_qf<<<dim3(256, 8), 256, 0, stream>>>(Q, W, bias, out, 1);
    }
    k_attn2<<<dim3(16, 32), 512, 0, stream>>>(Khi, Klo, M, out);
    k_pv2<<<dim3(8, 32), 512, 0, stream>>>(KhiT, out, 0);
    k_pv2<<<dim3(8, 32), 512, 0, stream>>>(KhiT, out, 1);
  } else {
    k_qf<<<dim3(256, 8), 256, 0, stream>>>(Q, W, bias, out, 0);
    k_attn<<<dim3(16, 32), 512, 0, stream>>>(K, M, out);
    k_pv<<<dim3(8, 32), 512, 0, stream>>>(K, out, 0);
    k_pv<<<dim3(8, 32), 512, 0, stream>>>(K, out, 1);
  }
}

// Round 3
// 819.982 us; speedup vs baseline: 1.7749x; 1.7749x over previous
//
#include <hip/hip_runtime.h>
#include <hip/hip_bf16.h>

// WordSentAtt: qf = relu(Q@W^T + b); S = qf@K^T (masked); attn = softmax; O = attn@K
// B=32, Lq=Lk=D=1024, f32 in/out. Split-bf16 (hi/lo) MFMA for qf and S.
// Tier A (ws>=340MB): pre-convert K(hi,lo,hiT),Q(hi,lo),W(hi,lo) once into ws;
//   all GEMMs use global_load_lds bf16 staging. qf stored packed [hi|lo] u16
//   rows in d_out; attn bf16 overwrites the lo half; k_pv2 (2 launches,
//   d-halves) writes final f32 O.
// R3 fixes vs R2: (1) k_attn2 kt loop FULLY unrolled -- R2's "#pragma unroll 1"
//   made acc[kt] runtime-indexed -> scratch spill (VGPR=40, 3.8GB HBM traffic).
// (2) k_qf2 XCD swizzle orientation: XCD owns m-band (Q streamed once,
//   W hi/lo 4MB L2-resident), not n-band (which streamed all Q per XCD).

typedef __attribute__((ext_vector_type(4))) float f32x4;
typedef __attribute__((ext_vector_type(8))) short s16x8;

#define MFMA16(a, b, c) __builtin_amdgcn_mfma_f32_16x16x32_bf16((a), (b), (c), 0, 0, 0)

__device__ __forceinline__ unsigned short f2bf(float x) {
  unsigned u = __builtin_bit_cast(unsigned, x);
  return (unsigned short)((u + 0x7FFFu + ((u >> 16) & 1u)) >> 16);
}
__device__ __forceinline__ float bf2f(unsigned short h) {
  return __builtin_bit_cast(float, ((unsigned)h) << 16);
}
__device__ __forceinline__ int swz(int row, int col) {
  return (row * 64 + col) ^ ((row & 7) << 3);
}
__device__ __forceinline__ void cvt8(const float* __restrict__ s, s16x8& h8, s16x8& l8) {
  f32x4 a = *(const f32x4*)s;
  f32x4 b = *(const f32x4*)(s + 4);
#pragma unroll
  for (int i = 0; i < 8; i++) {
    float v = (i < 4) ? a[i] : b[i - 4];
    unsigned short hu = f2bf(v);
    unsigned short lu = f2bf(v - bf2f(hu));
    h8[i] = (short)hu;
    l8[i] = (short)lu;
  }
}
__device__ __forceinline__ void gld16(const void* g, void* lds) {
  __builtin_amdgcn_global_load_lds((const __attribute__((address_space(1))) unsigned int*)g,
                                   (__attribute__((address_space(3))) unsigned int*)lds, 16, 0, 0);
}

// ws layout (bytes)
#define OFF_KHI 0ULL
#define OFF_KLO 67108864ULL
#define OFF_KHIT 134217728ULL
#define OFF_QHI 201326592ULL
#define OFF_QLO 268435456ULL
#define OFF_WHI 335544320ULL
#define OFF_WLO 337641472ULL
#define WS_TIER_A 339738624ULL
#define WS_TIER_B2 201326592ULL

// ================= Tier A pre-convert kernels =================
__global__ __launch_bounds__(256) void k_cvt_pair(const float* __restrict__ src,
                                                  unsigned short* __restrict__ hi,
                                                  unsigned short* __restrict__ lo, int n8) {
  int i = blockIdx.x * 256 + threadIdx.x;
  if (i >= n8) return;
  s16x8 h, l;
  cvt8(src + (size_t)i * 8, h, l);
  *(s16x8*)(hi + (size_t)i * 8) = h;
  *(s16x8*)(lo + (size_t)i * 8) = l;
}

// K[b][k][d] f32 -> Khi/Klo [b][k][d] u16 + KhiT [b][d][k] u16 (LDS transpose)
__global__ __launch_bounds__(256) void k_cvt_k(const float* __restrict__ K,
                                               unsigned short* __restrict__ Khi,
                                               unsigned short* __restrict__ Klo,
                                               unsigned short* __restrict__ KhiT) {
  __shared__ unsigned T[64 * 65];
  const int t = threadIdx.x;
  const int db0 = blockIdx.x * 64, kb0 = blockIdx.y * 64, b = blockIdx.z;
  const size_t base = (size_t)b * 1024 * 1024;
#pragma unroll
  for (int i = 0; i < 2; i++) {
    const int r = (t >> 3) + i * 32, c0 = (t & 7) * 8;
    s16x8 h, l;
    cvt8(K + base + (size_t)(kb0 + r) * 1024 + db0 + c0, h, l);
    *(s16x8*)(Khi + base + (size_t)(kb0 + r) * 1024 + db0 + c0) = h;
    *(s16x8*)(Klo + base + (size_t)(kb0 + r) * 1024 + db0 + c0) = l;
#pragma unroll
    for (int j = 0; j < 8; j++)
      T[r * 65 + c0 + j] = ((unsigned)(unsigned short)h[j] << 16) | (unsigned short)l[j];
  }
  __syncthreads();
#pragma unroll
  for (int i = 0; i < 2; i++) {
    const int rd = (t >> 3) + i * 32, ck0 = (t & 7) * 8;
    s16x8 h;
#pragma unroll
    for (int j = 0; j < 8; j++) h[j] = (short)(unsigned short)(T[(ck0 + j) * 65 + rd] >> 16);
    *(s16x8*)(KhiT + base + (size_t)(db0 + rd) * 1024 + kb0 + ck0) = h;
  }
}

// ================= Tier A: qf GEMM =================
// grid (256,8) = 2048 blocks, 256 thr = 4 waves (2x2). 128x128 tile, BK=64.
// XCD x (= i&7) owns m-tiles [x*32, x*32+32); n cycles fastest (W L2-resident).
__global__ __launch_bounds__(256, 2) void k_qf2(const unsigned short* __restrict__ Qhi,
                                                const unsigned short* __restrict__ Qlo,
                                                const unsigned short* __restrict__ Whi,
                                                const unsigned short* __restrict__ Wlo,
                                                const float* __restrict__ bias,
                                                float* __restrict__ outp) {
  __shared__ __align__(16) unsigned short Ah[128 * 64], Al[128 * 64], Bh[128 * 64], Bl[128 * 64];
  const int t = threadIdx.x;
  const int i = blockIdx.x + blockIdx.y * 256;
  const int x = i & 7, j = i >> 3;
  const int n0 = (j & 7) * 128;
  const int m0 = (x * 32 + (j >> 3)) * 128;
  const int w = t >> 6, l = t & 63, wm = w >> 1, wn = w & 1, g = l >> 4, ln = l & 15;
  const int lrow = l >> 3, lc8 = (l & 7) * 8;
  const f32x4 fz = {0.f, 0.f, 0.f, 0.f};
  f32x4 acc[4][4];
#pragma unroll
  for (int a = 0; a < 4; a++)
#pragma unroll
    for (int bq = 0; bq < 4; bq++) acc[a][bq] = fz;
#pragma unroll 1
  for (int k0 = 0; k0 < 1024; k0 += 64) {
#pragma unroll
    for (int jj = 0; jj < 4; jj++) {
      const int ch = w * 4 + jj;
      const int row = ch * 8 + lrow;
      const int sc = lc8 ^ (lrow << 3);  // source pre-swizzle (T2, rule 21)
      gld16(Qhi + (size_t)(m0 + row) * 1024 + k0 + sc, &Ah[ch * 512]);
      gld16(Qlo + (size_t)(m0 + row) * 1024 + k0 + sc, &Al[ch * 512]);
      gld16(Whi + (size_t)(n0 + row) * 1024 + k0 + sc, &Bh[ch * 512]);
      gld16(Wlo + (size_t)(n0 + row) * 1024 + k0 + sc, &Bl[ch * 512]);
    }
    __syncthreads();
#pragma unroll
    for (int ks = 0; ks < 2; ks++) {
      const int kc = ks * 32 + g * 8;
      s16x8 ah[4], al[4], bh[4], bl[4];
#pragma unroll
      for (int mf = 0; mf < 4; mf++) {
        const int row = wm * 64 + mf * 16 + ln;
        const int idx = row * 64 + (kc ^ ((row & 7) << 3));
        ah[mf] = *(const s16x8*)&Ah[idx];
        al[mf] = *(const s16x8*)&Al[idx];
      }
#pragma unroll
      for (int nf = 0; nf < 4; nf++) {
        const int row = wn * 64 + nf * 16 + ln;
        const int idx = row * 64 + (kc ^ ((row & 7) << 3));
        bh[nf] = *(const s16x8*)&Bh[idx];
        bl[nf] = *(const s16x8*)&Bl[idx];
      }
#pragma unroll
      for (int mf = 0; mf < 4; mf++)
#pragma unroll
        for (int nf = 0; nf < 4; nf++) {
          acc[mf][nf] = MFMA16(ah[mf], bh[nf], acc[mf][nf]);
          acc[mf][nf] = MFMA16(ah[mf], bl[nf], acc[mf][nf]);
          acc[mf][nf] = MFMA16(al[mf], bh[nf], acc[mf][nf]);
        }
    }
    __syncthreads();
  }
  unsigned short* oc = (unsigned short*)outp;
#pragma unroll
  for (int nf = 0; nf < 4; nf++) {
    const int col = n0 + wn * 64 + nf * 16 + ln;
    const float bv = bias[col];
#pragma unroll
    for (int mf = 0; mf < 4; mf++)
#pragma unroll
      for (int r = 0; r < 4; r++) {
        const int row = m0 + wm * 64 + mf * 16 + g * 4 + r;
        float v = acc[mf][nf][r] + bv;
        v = v > 0.f ? v : 0.f;
        unsigned short h = f2bf(v);
        oc[(size_t)row * 2048 + col] = h;
        oc[(size_t)row * 2048 + 1024 + col] = f2bf(v - bf2f(h));
      }
  }
}

// ================= Tier A: score GEMM + masked softmax =================
// grid (16,32) = 512 blocks, 512 thr = 8 waves (2 wm x 4 wn). S[64][1024] in regs.
__global__ __launch_bounds__(512, 2) void k_attn2(const unsigned short* __restrict__ Khi,
                                                  const unsigned short* __restrict__ Klo,
                                                  const float* __restrict__ mask,
                                                  float* __restrict__ dout) {
  __shared__ __align__(16) unsigned short qh[64 * 64], ql[64 * 64], kh[128 * 64], kl[128 * 64];
  __shared__ float mask_s[1024];
  __shared__ float red[4][64];
  const int t = threadIdx.x;
  const int i = blockIdx.y * 16 + blockIdx.x;
  const int x = i & 7, jj = i >> 3;
  const int b = x * 4 + (jj >> 4), qt = jj & 15;
  const int q0 = qt * 64;
  const int w = t >> 6, l = t & 63, wm = w >> 2, wn = w & 3, g = l >> 4, ln = l & 15;
  const int lrow = l >> 3, lc8 = (l & 7) * 8, sc = lc8 ^ (lrow << 3);
  for (int ii = t; ii < 1024; ii += 512) mask_s[ii] = mask[b * 1024 + ii];
  const f32x4 fz = {0.f, 0.f, 0.f, 0.f};
  f32x4 acc[8][2][2];
#pragma unroll
  for (int kt = 0; kt < 8; kt++)
#pragma unroll
    for (int mf = 0; mf < 2; mf++)
#pragma unroll
      for (int nf = 0; nf < 2; nf++) acc[kt][mf][nf] = fz;
  const unsigned short* dou16 = (const unsigned short*)dout;
  const size_t kbase = (size_t)b * 1024 * 1024;
#pragma unroll 1
  for (int dc = 0; dc < 16; dc++) {
    {  // stage q planes (64x64): 8 chunks, 1/wave/plane
      const int row = w * 8 + lrow;
      const unsigned short* gq = dou16 + (size_t)(b * 1024 + q0 + row) * 2048 + dc * 64 + sc;
      gld16(gq, &qh[w * 512]);
      gld16(gq + 1024, &ql[w * 512]);
    }
#pragma unroll  // MUST be full: acc[kt] needs compile-time kt (rule #20; R2 spilled)
    for (int kt = 0; kt < 8; kt++) {
#pragma unroll
      for (int jj2 = 0; jj2 < 2; jj2++) {  // stage k planes (128x64): 16 chunks
        const int ch = w * 2 + jj2;
        const int row = ch * 8 + lrow;
        const size_t go = kbase + (size_t)(kt * 128 + row) * 1024 + dc * 64 + sc;
        gld16(Khi + go, &kh[ch * 512]);
        gld16(Klo + go, &kl[ch * 512]);
      }
      __syncthreads();
#pragma unroll
      for (int ks = 0; ks < 2; ks++) {
        const int kc = ks * 32 + g * 8;
        s16x8 ah[2], al2[2], bh[2], bl[2];
#pragma unroll
        for (int mf = 0; mf < 2; mf++) {
          const int row = wm * 32 + mf * 16 + ln;
          const int idx = row * 64 + (kc ^ ((row & 7) << 3));
          ah[mf] = *(const s16x8*)&qh[idx];
          al2[mf] = *(const s16x8*)&ql[idx];
        }
#pragma unroll
        for (int nf = 0; nf < 2; nf++) {
          const int row = wn * 32 + nf * 16 + ln;
          const int idx = row * 64 + (kc ^ ((row & 7) << 3));
          bh[nf] = *(const s16x8*)&kh[idx];
          bl[nf] = *(const s16x8*)&kl[idx];
        }
#pragma unroll
        for (int mf = 0; mf < 2; mf++)
#pragma unroll
          for (int nf = 0; nf < 2; nf++) {
            acc[kt][mf][nf] = MFMA16(ah[mf], bh[nf], acc[kt][mf][nf]);
            acc[kt][mf][nf] = MFMA16(ah[mf], bl[nf], acc[kt][mf][nf]);
            acc[kt][mf][nf] = MFMA16(al2[mf], bh[nf], acc[kt][mf][nf]);
          }
      }
      __syncthreads();
    }
  }
  // ---- masked softmax ----
  float rmax[2][4];
#pragma unroll
  for (int mf = 0; mf < 2; mf++)
#pragma unroll
    for (int r = 0; r < 4; r++) rmax[mf][r] = -1e30f;
#pragma unroll
  for (int kt = 0; kt < 8; kt++)
#pragma unroll
    for (int nf = 0; nf < 2; nf++) {
      const int k = kt * 128 + wn * 32 + nf * 16 + ln;
      const bool mk = mask_s[k] != 0.f;
#pragma unroll
      for (int mf = 0; mf < 2; mf++)
#pragma unroll
        for (int r = 0; r < 4; r++)
          if (mk) rmax[mf][r] = fmaxf(rmax[mf][r], acc[kt][mf][nf][r]);
    }
#pragma unroll
  for (int off = 1; off < 16; off <<= 1)
#pragma unroll
    for (int mf = 0; mf < 2; mf++)
#pragma unroll
      for (int r = 0; r < 4; r++) rmax[mf][r] = fmaxf(rmax[mf][r], __shfl_xor(rmax[mf][r], off));
  if (ln == 0) {
#pragma unroll
    for (int mf = 0; mf < 2; mf++)
#pragma unroll
      for (int r = 0; r < 4; r++) red[wn][wm * 32 + mf * 16 + g * 4 + r] = rmax[mf][r];
  }
  __syncthreads();
#pragma unroll
  for (int mf = 0; mf < 2; mf++)
#pragma unroll
    for (int r = 0; r < 4; r++) {
      const int row = wm * 32 + mf * 16 + g * 4 + r;
      rmax[mf][r] = fmaxf(fmaxf(red[0][row], red[1][row]), fmaxf(red[2][row], red[3][row]));
    }
  __syncthreads();
  float rsum[2][4];
#pragma unroll
  for (int mf = 0; mf < 2; mf++)
#pragma unroll
    for (int r = 0; r < 4; r++) rsum[mf][r] = 0.f;
#pragma unroll
  for (int kt = 0; kt < 8; kt++)
#pragma unroll
    for (int nf = 0; nf < 2; nf++) {
      const int k = kt * 128 + wn * 32 + nf * 16 + ln;
      const bool mk = mask_s[k] != 0.f;
#pragma unroll
      for (int mf = 0; mf < 2; mf++)
#pragma unroll
        for (int r = 0; r < 4; r++)
          if (mk) rsum[mf][r] += __expf(acc[kt][mf][nf][r] - rmax[mf][r]);
    }
#pragma unroll
  for (int off = 1; off < 16; off <<= 1)
#pragma unroll
    for (int mf = 0; mf < 2; mf++)
#pragma unroll
      for (int r = 0; r < 4; r++) rsum[mf][r] += __shfl_xor(rsum[mf][r], off);
  if (ln == 0) {
#pragma unroll
    for (int mf = 0; mf < 2; mf++)
#pragma unroll
      for (int r = 0; r < 4; r++) red[wn][wm * 32 + mf * 16 + g * 4 + r] = rsum[mf][r];
  }
  __syncthreads();
  float rinv[2][4];
#pragma unroll
  for (int mf = 0; mf < 2; mf++)
#pragma unroll
    for (int r = 0; r < 4; r++) {
      const int row = wm * 32 + mf * 16 + g * 4 + r;
      rinv[mf][r] = 1.f / (red[0][row] + red[1][row] + red[2][row] + red[3][row]);
    }
  unsigned short* oc = (unsigned short*)dout;
#pragma unroll
  for (int kt = 0; kt < 8; kt++)
#pragma unroll
    for (int nf = 0; nf < 2; nf++) {
      const int k = kt * 128 + wn * 32 + nf * 16 + ln;
      const bool mk = mask_s[k] != 0.f;
#pragma unroll
      for (int mf = 0; mf < 2; mf++)
#pragma unroll
        for (int r = 0; r < 4; r++) {
          const int q = q0 + wm * 32 + mf * 16 + g * 4 + r;
          float p = mk ? __expf(acc[kt][mf][nf][r] - rmax[mf][r]) * rinv[mf][r] : 0.f;
          oc[(size_t)(b * 1024 + q) * 2048 + 1024 + k] = f2bf(p);
        }
    }
}

// ================= Tier A: O = attn @ K via KhiT =================
// grid (8,32) = 256 blocks, 512 thr = 8 waves (2 wm x 4 wd). 128q x 512d, BK=64.
__global__ __launch_bounds__(512, 2) void k_pv2(const unsigned short* __restrict__ KhiT,
                                                float* __restrict__ dout, const int dh) {
  __shared__ __align__(16) unsigned short P[128 * 64];
  __shared__ __align__(16) unsigned short KT[512 * 64];
  const int t = threadIdx.x;
  const int i = blockIdx.y * 8 + blockIdx.x;
  const int x = i & 7, jj = i >> 3;
  const int b = x * 4 + (jj >> 3), qt = jj & 7;
  const int q0 = qt * 128, d0 = dh * 512;
  const int w = t >> 6, l = t & 63, wm = w >> 2, wd = w & 3, g = l >> 4, ln = l & 15;
  const int lrow = l >> 3, lc8 = (l & 7) * 8, sc = lc8 ^ (lrow << 3);
  const f32x4 fz = {0.f, 0.f, 0.f, 0.f};
  f32x4 acc[4][8];
#pragma unroll
  for (int a = 0; a < 4; a++)
#pragma unroll
    for (int bq = 0; bq < 8; bq++) acc[a][bq] = fz;
  const unsigned short* dou16 = (const unsigned short*)dout;
  const size_t kbase = (size_t)b * 1024 * 1024;
#pragma unroll 1
  for (int k0 = 0; k0 < 1024; k0 += 64) {
#pragma unroll
    for (int jj2 = 0; jj2 < 2; jj2++) {  // P: 16 chunks
      const int ch = w * 2 + jj2;
      const int row = ch * 8 + lrow;
      gld16(dou16 + (size_t)(b * 1024 + q0 + row) * 2048 + 1024 + k0 + sc, &P[ch * 512]);
    }
#pragma unroll
    for (int jj2 = 0; jj2 < 8; jj2++) {  // KT: 64 chunks
      const int ch = w * 8 + jj2;
      const int row = ch * 8 + lrow;
      gld16(KhiT + kbase + (size_t)(d0 + row) * 1024 + k0 + sc, &KT[ch * 512]);
    }
    __syncthreads();
#pragma unroll
    for (int ks = 0; ks < 2; ks++) {
      const int kc = ks * 32 + g * 8;
      s16x8 a[4], bb[8];
#pragma unroll
      for (int mf = 0; mf < 4; mf++) {
        const int row = wm * 64 + mf * 16 + ln;
        a[mf] = *(const s16x8*)&P[row * 64 + (kc ^ ((row & 7) << 3))];
      }
#pragma unroll
      for (int nf = 0; nf < 8; nf++) {
        const int row = wd * 128 + nf * 16 + ln;
        bb[nf] = *(const s16x8*)&KT[row * 64 + (kc ^ ((row & 7) << 3))];
      }
#pragma unroll
      for (int mf = 0; mf < 4; mf++)
#pragma unroll
        for (int nf = 0; nf < 8; nf++) acc[mf][nf] = MFMA16(a[mf], bb[nf], acc[mf][nf]);
    }
    __syncthreads();
  }
#pragma unroll
  for (int mf = 0; mf < 4; mf++)
#pragma unroll
    for (int nf = 0; nf < 8; nf++)
#pragma unroll
      for (int r = 0; r < 4; r++) {
        const int q = q0 + wm * 64 + mf * 16 + g * 4 + r;
        const int d = d0 + wd * 128 + nf * 16 + ln;
        dout[(size_t)(b * 1024 + q) * 1024 + d] = acc[mf][nf][r];
      }
}

// ================= Tier B/C: round-1 kernels (fallback) =================
__global__ __launch_bounds__(256, 2) void k_qf(const float* __restrict__ Q,
                                               const float* __restrict__ W,
                                               const float* __restrict__ bias,
                                               float* __restrict__ qf, const int packout) {
  __shared__ __align__(16) short Ah[128 * 64], Al[128 * 64], Bh[128 * 64], Bl[128 * 64];
  const int t = threadIdx.x;
  const int m0 = blockIdx.x * 128, n0 = blockIdx.y * 128;
  const int w = t >> 6, l = t & 63, wm = w >> 1, wn = w & 1, g = l >> 4, ln = l & 15;
  const f32x4 fz = {0.f, 0.f, 0.f, 0.f};
  f32x4 acc[4][4];
#pragma unroll
  for (int a = 0; a < 4; a++)
#pragma unroll
    for (int bq = 0; bq < 4; bq++) acc[a][bq] = fz;
  const int srow = t >> 1, scol = (t & 1) * 32;
#pragma unroll 1
  for (int k0 = 0; k0 < 1024; k0 += 64) {
    const float* sa = Q + (size_t)(m0 + srow) * 1024 + k0 + scol;
    const float* sb = W + (size_t)(n0 + srow) * 1024 + k0 + scol;
#pragma unroll
    for (int c = 0; c < 32; c += 8) {
      s16x8 h, lo;
      cvt8(sa + c, h, lo);
      int si = swz(srow, scol + c);
      *(s16x8*)&Ah[si] = h;
      *(s16x8*)&Al[si] = lo;
    }
#pragma unroll
    for (int c = 0; c < 32; c += 8) {
      s16x8 h, lo;
      cvt8(sb + c, h, lo);
      int si = swz(srow, scol + c);
      *(s16x8*)&Bh[si] = h;
      *(s16x8*)&Bl[si] = lo;
    }
    __syncthreads();
#pragma unroll
    for (int ks = 0; ks < 2; ks++) {
      const int kc = ks * 32 + g * 8;
      s16x8 ah[4], al[4], bh[4], bl[4];
#pragma unroll
      for (int mf = 0; mf < 4; mf++) {
        int si = swz(wm * 64 + mf * 16 + ln, kc);
        ah[mf] = *(s16x8*)&Ah[si];
        al[mf] = *(s16x8*)&Al[si];
      }
#pragma unroll
      for (int nf = 0; nf < 4; nf++) {
        int si = swz(wn * 64 + nf * 16 + ln, kc);
        bh[nf] = *(s16x8*)&Bh[si];
        bl[nf] = *(s16x8*)&Bl[si];
      }
#pragma unroll
      for (int mf = 0; mf < 4; mf++)
#pragma unroll
        for (int nf = 0; nf < 4; nf++) {
          acc[mf][nf] = MFMA16(ah[mf], bh[nf], acc[mf][nf]);
          acc[mf][nf] = MFMA16(ah[mf], bl[nf], acc[mf][nf]);
          acc[mf][nf] = MFMA16(al[mf], bh[nf], acc[mf][nf]);
        }
    }
    __syncthreads();
  }
  unsigned short* oc = (unsigned short*)qf;
#pragma unroll
  for (int nf = 0; nf < 4; nf++) {
    const int col = n0 + wn * 64 + nf * 16 + ln;
    const float bv = bias[col];
#pragma unroll
    for (int mf = 0; mf < 4; mf++)
#pragma unroll
      for (int r = 0; r < 4; r++) {
        const int row = m0 + wm * 64 + mf * 16 + g * 4 + r;
        float v = acc[mf][nf][r] + bv;
        v = v > 0.f ? v : 0.f;
        if (packout) {
          unsigned short h = f2bf(v);
          oc[(size_t)row * 2048 + col] = h;
          oc[(size_t)row * 2048 + 1024 + col] = f2bf(v - bf2f(h));
        } else {
          qf[(size_t)row * 1024 + col] = v;
        }
      }
  }
}

__global__ __launch_bounds__(512, 2) void k_attn(const float* __restrict__ Key,
                                                 const float* __restrict__ mask,
                                                 float* __restrict__ dout) {
  __shared__ __align__(16) short qh[64 * 64], qlo[64 * 64], kh[128 * 64], klo[128 * 64];
  __shared__ float mask_s[1024];
  __shared__ float red[4][64];
  const int t = threadIdx.x;
  const int qt = blockIdx.x, b = blockIdx.y;
  const int q0 = qt * 64;
  const int w = t >> 6, l = t & 63, wm = w >> 2, wn = w & 3, g = l >> 4, ln = l & 15;
  for (int i = t; i < 1024; i += 512) mask_s[i] = mask[b * 1024 + i];
  const f32x4 fz = {0.f, 0.f, 0.f, 0.f};
  f32x4 acc[8][2][2];
#pragma unroll
  for (int kt = 0; kt < 8; kt++)
#pragma unroll
    for (int mf = 0; mf < 2; mf++)
#pragma unroll
      for (int nf = 0; nf < 2; nf++) acc[kt][mf][nf] = fz;
  const float* qfb = dout + (size_t)(b * 1024 + q0) * 1024;
  const float* kb = Key + (size_t)b * 1024 * 1024;
  const int qrow = t >> 3, qcol = (t & 7) * 8;
  const int krow = t >> 2, kcol0 = (t & 3) * 16;
#pragma unroll 1
  for (int dc = 0; dc < 16; dc++) {
    {
      s16x8 h, lo;
      cvt8(qfb + (size_t)qrow * 1024 + dc * 64 + qcol, h, lo);
      int si = swz(qrow, qcol);
      *(s16x8*)&qh[si] = h;
      *(s16x8*)&qlo[si] = lo;
    }
#pragma unroll
    for (int kt = 0; kt < 8; kt++) {
      {
        const float* s = kb + (size_t)(kt * 128 + krow) * 1024 + dc * 64 + kcol0;
        s16x8 h, lo;
        cvt8(s, h, lo);
        int si = swz(krow, kcol0);
        *(s16x8*)&kh[si] = h;
        *(s16x8*)&klo[si] = lo;
        cvt8(s + 8, h, lo);
        si = swz(krow, kcol0 + 8);
        *(s16x8*)&kh[si] = h;
        *(s16x8*)&klo[si] = lo;
      }
      __syncthreads();
#pragma unroll
      for (int ks = 0; ks < 2; ks++) {
        const int kc = ks * 32 + g * 8;
        s16x8 ah[2], al2[2], bh[2], bl[2];
#pragma unroll
        for (int mf = 0; mf < 2; mf++) {
          int si = swz(wm * 32 + mf * 16 + ln, kc);
          ah[mf] = *(s16x8*)&qh[si];
          al2[mf] = *(s16x8*)&qlo[si];
        }
#pragma unroll
        for (int nf = 0; nf < 2; nf++) {
          int si = swz(wn * 32 + nf * 16 + ln, kc);
          bh[nf] = *(s16x8*)&kh[si];
          bl[nf] = *(s16x8*)&klo[si];
        }
#pragma unroll
        for (int mf = 0; mf < 2; mf++)
#pragma unroll
          for (int nf = 0; nf < 2; nf++) {
            acc[kt][mf][nf] = MFMA16(ah[mf], bh[nf], acc[kt][mf][nf]);
            acc[kt][mf][nf] = MFMA16(ah[mf], bl[nf], acc[kt][mf][nf]);
            acc[kt][mf][nf] = MFMA16(al2[mf], bh[nf], acc[kt][mf][nf]);
          }
      }
      __syncthreads();
    }
  }
  float rmax[2][4];
#pragma unroll
  for (int mf = 0; mf < 2; mf++)
#pragma unroll
    for (int r = 0; r < 4; r++) rmax[mf][r] = -1e30f;
#pragma unroll
  for (int kt = 0; kt < 8; kt++)
#pragma unroll
    for (int nf = 0; nf < 2; nf++) {
      const int k = kt * 128 + wn * 32 + nf * 16 + ln;
      const bool mk = mask_s[k] != 0.f;
#pragma unroll
      for (int mf = 0; mf < 2; mf++)
#pragma unroll
        for (int r = 0; r < 4; r++)
          if (mk) rmax[mf][r] = fmaxf(rmax[mf][r], acc[kt][mf][nf][r]);
    }
#pragma unroll
  for (int off = 1; off < 16; off <<= 1)
#pragma unroll
    for (int mf = 0; mf < 2; mf++)
#pragma unroll
      for (int r = 0; r < 4; r++) rmax[mf][r] = fmaxf(rmax[mf][r], __shfl_xor(rmax[mf][r], off));
  if (ln == 0) {
#pragma unroll
    for (int mf = 0; mf < 2; mf++)
#pragma unroll
      for (int r = 0; r < 4; r++) red[wn][wm * 32 + mf * 16 + g * 4 + r] = rmax[mf][r];
  }
  __syncthreads();
#pragma unroll
  for (int mf = 0; mf < 2; mf++)
#pragma unroll
    for (int r = 0; r < 4; r++) {
      const int row = wm * 32 + mf * 16 + g * 4 + r;
      rmax[mf][r] = fmaxf(fmaxf(red[0][row], red[1][row]), fmaxf(red[2][row], red[3][row]));
    }
  __syncthreads();
  float rsum[2][4];
#pragma unroll
  for (int mf = 0; mf < 2; mf++)
#pragma unroll
    for (int r = 0; r < 4; r++) rsum[mf][r] = 0.f;
#pragma unroll
  for (int kt = 0; kt < 8; kt++)
#pragma unroll
    for (int nf = 0; nf < 2; nf++) {
      const int k = kt * 128 + wn * 32 + nf * 16 + ln;
      const bool mk = mask_s[k] != 0.f;
#pragma unroll
      for (int mf = 0; mf < 2; mf++)
#pragma unroll
        for (int r = 0; r < 4; r++)
          if (mk) rsum[mf][r] += __expf(acc[kt][mf][nf][r] - rmax[mf][r]);
    }
#pragma unroll
  for (int off = 1; off < 16; off <<= 1)
#pragma unroll
    for (int mf = 0; mf < 2; mf++)
#pragma unroll
      for (int r = 0; r < 4; r++) rsum[mf][r] += __shfl_xor(rsum[mf][r], off);
  if (ln == 0) {
#pragma unroll
    for (int mf = 0; mf < 2; mf++)
#pragma unroll
      for (int r = 0; r < 4; r++) red[wn][wm * 32 + mf * 16 + g * 4 + r] = rsum[mf][r];
  }
  __syncthreads();
  float rinv[2][4];
#pragma unroll
  for (int mf = 0; mf < 2; mf++)
#pragma unroll
    for (int r = 0; r < 4; r++) {
      const int row = wm * 32 + mf * 16 + g * 4 + r;
      rinv[mf][r] = 1.f / (red[0][row] + red[1][row] + red[2][row] + red[3][row]);
    }
  char* oc = (char*)dout;
#pragma unroll
  for (int kt = 0; kt < 8; kt++)
#pragma unroll
    for (int nf = 0; nf < 2; nf++) {
      const int k = kt * 128 + wn * 32 + nf * 16 + ln;
      const bool mk = mask_s[k] != 0.f;
#pragma unroll
      for (int mf = 0; mf < 2; mf++)
#pragma unroll
        for (int r = 0; r < 4; r++) {
          const int q = q0 + wm * 32 + mf * 16 + g * 4 + r;
          float p = mk ? __expf(acc[kt][mf][nf][r] - rmax[mf][r]) * rinv[mf][r] : 0.f;
          *(unsigned short*)(oc + (size_t)(b * 1024 + q) * 4096 + 2048 + k * 2) = f2bf(p);
        }
    }
}

__global__ __launch_bounds__(512, 2) void k_pv(const float* __restrict__ Key,
                                               float* __restrict__ dout, const int dh) {
  __shared__ __align__(16) short P[128 * 64];
  __shared__ __align__(16) short KT[512 * 64];
  const int t = threadIdx.x;
  const int qt = blockIdx.x, b = blockIdx.y;
  const int q0 = qt * 128, d0 = dh * 512;
  const int w = t >> 6, l = t & 63, wm = w >> 2, wd = w & 3, g = l >> 4, ln = l & 15;
  const f32x4 fz = {0.f, 0.f, 0.f, 0.f};
  f32x4 acc[4][8];
#pragma unroll
  for (int a = 0; a < 4; a++)
#pragma unroll
    for (int bq = 0; bq < 8; bq++) acc[a][bq] = fz;
  const char* ab = (const char*)dout;
  const int prow = t >> 2, pc0 = (t & 3) * 16;
#pragma unroll 1
  for (int k0 = 0; k0 < 1024; k0 += 64) {
    {
      const unsigned short* s =
          (const unsigned short*)(ab + (size_t)(b * 1024 + q0 + prow) * 4096 + 2048) + k0 + pc0;
      s16x8 p0 = *(const s16x8*)s, p1 = *(const s16x8*)(s + 8);
      *(s16x8*)&P[swz(prow, pc0)] = p0;
      *(s16x8*)&P[swz(prow, pc0 + 8)] = p1;
    }
    {
      const float* ksrc = Key + (size_t)b * 1024 * 1024 + (size_t)k0 * 1024 + d0 + t;
#pragma unroll
      for (int kg = 0; kg < 8; kg++) {
        s16x8 h;
#pragma unroll
        for (int jx = 0; jx < 8; jx++) h[jx] = (short)f2bf(ksrc[(size_t)(kg * 8 + jx) * 1024]);
        *(s16x8*)&KT[swz(t, kg * 8)] = h;
      }
    }
    __syncthreads();
#pragma unroll
    for (int ks = 0; ks < 2; ks++) {
      const int kc = ks * 32 + g * 8;
      s16x8 a[4], bb[8];
#pragma unroll
      for (int mf = 0; mf < 4; mf++) a[mf] = *(s16x8*)&P[swz(wm * 64 + mf * 16 + ln, kc)];
#pragma unroll
      for (int nf = 0; nf < 8; nf++) bb[nf] = *(s16x8*)&KT[swz(wd * 128 + nf * 16 + ln, kc)];
#pragma unroll
      for (int mf = 0; mf < 4; mf++)
#pragma unroll
        for (int nf = 0; nf < 8; nf++) acc[mf][nf] = MFMA16(a[mf], bb[nf], acc[mf][nf]);
    }
    __syncthreads();
  }
#pragma unroll
  for (int mf = 0; mf < 4; mf++)
#pragma unroll
    for (int nf = 0; nf < 8; nf++)
#pragma unroll
      for (int r = 0; r < 4; r++) {
        const int q = q0 + wm * 64 + mf * 16 + g * 4 + r;
        const int d = d0 + wd * 128 + nf * 16 + ln;
        dout[(size_t)(b * 1024 + q) * 1024 + d] = acc[mf][nf][r];
      }
}

extern "C" void kernel_launch(void* const* d_in, const int* in_sizes, int n_in,
                              void* d_out, int out_size, void* d_ws, size_t ws_size,
                              hipStream_t stream) {
  const float* Q = (const float*)d_in[0];
  const float* K = (const float*)d_in[1];
  const float* M = (const float*)d_in[2];
  const float* W = (const float*)d_in[3];
  const float* bias = (const float*)d_in[4];
  float* out = (float*)d_out;
  char* wsb = (char*)d_ws;
  (void)in_sizes; (void)n_in; (void)out_size;

  const bool tierA = ws_size >= WS_TIER_A;
  const bool tierB2 = !tierA && ws_size >= WS_TIER_B2;
  if (tierA || tierB2) {
    unsigned short* Khi = (unsigned short*)(wsb + OFF_KHI);
    unsigned short* Klo = (unsigned short*)(wsb + OFF_KLO);
    unsigned short* KhiT = (unsigned short*)(wsb + OFF_KHIT);
    k_cvt_k<<<dim3(16, 16, 32), 256, 0, stream>>>(K, Khi, Klo, KhiT);
    if (tierA) {
      unsigned short* Qhi = (unsigned short*)(wsb + OFF_QHI);
      unsigned short* Qlo = (unsigned short*)(wsb + OFF_QLO);
      unsigned short* Whi = (unsigned short*)(wsb + OFF_WHI);
      unsigned short* Wlo = (unsigned short*)(wsb + OFF_WLO);
      k_cvt_pair<<<16384, 256, 0, stream>>>(Q, Qhi, Qlo, 4194304);
      k_cvt_pair<<<512, 256, 0, stream>>>(W, Whi, Wlo, 131072);
      k_qf2<<<dim3(256, 8), 256, 0, stream>>>(Qhi, Qlo, Whi, Wlo, bias, out);
    } else {
      k_qf<<<dim3(256, 8), 256, 0, stream>>>(Q, W, bias, out, 1);
    }
    k_attn2<<<dim3(16, 32), 512, 0, stream>>>(Khi, Klo, M, out);
    k_pv2<<<dim3(8, 32), 512, 0, stream>>>(KhiT, out, 0);
    k_pv2<<<dim3(8, 32), 512, 0, stream>>>(KhiT, out, 1);
  } else {
    k_qf<<<dim3(256, 8), 256, 0, stream>>>(Q, W, bias, out, 0);
    k_attn<<<dim3(16, 32), 512, 0, stream>>>(K, M, out);
    k_pv<<<dim3(8, 32), 512, 0, stream>>>(K, out, 0);
    k_pv<<<dim3(8, 32), 512, 0, stream>>>(K, out, 1);
  }
}

// Round 4
// 800.995 us; speedup vs baseline: 1.8170x; 1.0237x over previous
//
#include <hip/hip_runtime.h>
#include <hip/hip_bf16.h>

// WordSentAtt: qf = relu(Q@W^T + b); S = qf@K^T (masked); attn = softmax; O = attn@K
// B=32, Lq=Lk=D=1024, f32 in/out. Split-bf16 (hi/lo) MFMA for qf and S.
// Tier A (ws>=340MB): pre-convert K(hi,lo,hiT),Q(hi,lo),W(hi,lo) once into ws.
// R4: k_attn2 restructured as 2-phase prefetch pipeline (T3-minimum, m248):
//   - K LDS double-buffered; STAGE(next) issued BEFORE compute(cur); ONE
//     __syncthreads per segment (its vmcnt(0) drain covers the prefetch).
//   - q-fragments in REGISTERS (direct global loads per dc; no q LDS, no
//     q staging barrier). LDS = 64KB kbuf + mask + red => 2 blocks/CU.

typedef __attribute__((ext_vector_type(4))) float f32x4;
typedef __attribute__((ext_vector_type(8))) short s16x8;

#define MFMA16(a, b, c) __builtin_amdgcn_mfma_f32_16x16x32_bf16((a), (b), (c), 0, 0, 0)

__device__ __forceinline__ unsigned short f2bf(float x) {
  unsigned u = __builtin_bit_cast(unsigned, x);
  return (unsigned short)((u + 0x7FFFu + ((u >> 16) & 1u)) >> 16);
}
__device__ __forceinline__ float bf2f(unsigned short h) {
  return __builtin_bit_cast(float, ((unsigned)h) << 16);
}
__device__ __forceinline__ int swz(int row, int col) {
  return (row * 64 + col) ^ ((row & 7) << 3);
}
__device__ __forceinline__ void cvt8(const float* __restrict__ s, s16x8& h8, s16x8& l8) {
  f32x4 a = *(const f32x4*)s;
  f32x4 b = *(const f32x4*)(s + 4);
#pragma unroll
  for (int i = 0; i < 8; i++) {
    float v = (i < 4) ? a[i] : b[i - 4];
    unsigned short hu = f2bf(v);
    unsigned short lu = f2bf(v - bf2f(hu));
    h8[i] = (short)hu;
    l8[i] = (short)lu;
  }
}
__device__ __forceinline__ void gld16(const void* g, void* lds) {
  __builtin_amdgcn_global_load_lds((const __attribute__((address_space(1))) unsigned int*)g,
                                   (__attribute__((address_space(3))) unsigned int*)lds, 16, 0, 0);
}

// ws layout (bytes)
#define OFF_KHI 0ULL
#define OFF_KLO 67108864ULL
#define OFF_KHIT 134217728ULL
#define OFF_QHI 201326592ULL
#define OFF_QLO 268435456ULL
#define OFF_WHI 335544320ULL
#define OFF_WLO 337641472ULL
#define WS_TIER_A 339738624ULL
#define WS_TIER_B2 201326592ULL

// ================= Tier A pre-convert kernels =================
__global__ __launch_bounds__(256) void k_cvt_pair(const float* __restrict__ src,
                                                  unsigned short* __restrict__ hi,
                                                  unsigned short* __restrict__ lo, int n8) {
  int i = blockIdx.x * 256 + threadIdx.x;
  if (i >= n8) return;
  s16x8 h, l;
  cvt8(src + (size_t)i * 8, h, l);
  *(s16x8*)(hi + (size_t)i * 8) = h;
  *(s16x8*)(lo + (size_t)i * 8) = l;
}

// K[b][k][d] f32 -> Khi/Klo [b][k][d] u16 + KhiT [b][d][k] u16 (LDS transpose)
__global__ __launch_bounds__(256) void k_cvt_k(const float* __restrict__ K,
                                               unsigned short* __restrict__ Khi,
                                               unsigned short* __restrict__ Klo,
                                               unsigned short* __restrict__ KhiT) {
  __shared__ unsigned T[64 * 65];
  const int t = threadIdx.x;
  const int db0 = blockIdx.x * 64, kb0 = blockIdx.y * 64, b = blockIdx.z;
  const size_t base = (size_t)b * 1024 * 1024;
#pragma unroll
  for (int i = 0; i < 2; i++) {
    const int r = (t >> 3) + i * 32, c0 = (t & 7) * 8;
    s16x8 h, l;
    cvt8(K + base + (size_t)(kb0 + r) * 1024 + db0 + c0, h, l);
    *(s16x8*)(Khi + base + (size_t)(kb0 + r) * 1024 + db0 + c0) = h;
    *(s16x8*)(Klo + base + (size_t)(kb0 + r) * 1024 + db0 + c0) = l;
#pragma unroll
    for (int j = 0; j < 8; j++)
      T[r * 65 + c0 + j] = ((unsigned)(unsigned short)h[j] << 16) | (unsigned short)l[j];
  }
  __syncthreads();
#pragma unroll
  for (int i = 0; i < 2; i++) {
    const int rd = (t >> 3) + i * 32, ck0 = (t & 7) * 8;
    s16x8 h;
#pragma unroll
    for (int j = 0; j < 8; j++) h[j] = (short)(unsigned short)(T[(ck0 + j) * 65 + rd] >> 16);
    *(s16x8*)(KhiT + base + (size_t)(db0 + rd) * 1024 + kb0 + ck0) = h;
  }
}

// ================= Tier A: qf GEMM =================
// grid (256,8) = 2048 blocks, 256 thr = 4 waves (2x2). 128x128 tile, BK=64.
// XCD x (= i&7) owns m-tiles [x*32, x*32+32); n cycles fastest (W L2-resident).
__global__ __launch_bounds__(256, 2) void k_qf2(const unsigned short* __restrict__ Qhi,
                                                const unsigned short* __restrict__ Qlo,
                                                const unsigned short* __restrict__ Whi,
                                                const unsigned short* __restrict__ Wlo,
                                                const float* __restrict__ bias,
                                                float* __restrict__ outp) {
  __shared__ __align__(16) unsigned short Ah[128 * 64], Al[128 * 64], Bh[128 * 64], Bl[128 * 64];
  const int t = threadIdx.x;
  const int i = blockIdx.x + blockIdx.y * 256;
  const int x = i & 7, j = i >> 3;
  const int n0 = (j & 7) * 128;
  const int m0 = (x * 32 + (j >> 3)) * 128;
  const int w = t >> 6, l = t & 63, wm = w >> 1, wn = w & 1, g = l >> 4, ln = l & 15;
  const int lrow = l >> 3, lc8 = (l & 7) * 8;
  const f32x4 fz = {0.f, 0.f, 0.f, 0.f};
  f32x4 acc[4][4];
#pragma unroll
  for (int a = 0; a < 4; a++)
#pragma unroll
    for (int bq = 0; bq < 4; bq++) acc[a][bq] = fz;
#pragma unroll 1
  for (int k0 = 0; k0 < 1024; k0 += 64) {
#pragma unroll
    for (int jj = 0; jj < 4; jj++) {
      const int ch = w * 4 + jj;
      const int row = ch * 8 + lrow;
      const int sc = lc8 ^ (lrow << 3);  // source pre-swizzle (T2, rule 21)
      gld16(Qhi + (size_t)(m0 + row) * 1024 + k0 + sc, &Ah[ch * 512]);
      gld16(Qlo + (size_t)(m0 + row) * 1024 + k0 + sc, &Al[ch * 512]);
      gld16(Whi + (size_t)(n0 + row) * 1024 + k0 + sc, &Bh[ch * 512]);
      gld16(Wlo + (size_t)(n0 + row) * 1024 + k0 + sc, &Bl[ch * 512]);
    }
    __syncthreads();
#pragma unroll
    for (int ks = 0; ks < 2; ks++) {
      const int kc = ks * 32 + g * 8;
      s16x8 ah[4], al[4], bh[4], bl[4];
#pragma unroll
      for (int mf = 0; mf < 4; mf++) {
        const int row = wm * 64 + mf * 16 + ln;
        const int idx = row * 64 + (kc ^ ((row & 7) << 3));
        ah[mf] = *(const s16x8*)&Ah[idx];
        al[mf] = *(const s16x8*)&Al[idx];
      }
#pragma unroll
      for (int nf = 0; nf < 4; nf++) {
        const int row = wn * 64 + nf * 16 + ln;
        const int idx = row * 64 + (kc ^ ((row & 7) << 3));
        bh[nf] = *(const s16x8*)&Bh[idx];
        bl[nf] = *(const s16x8*)&Bl[idx];
      }
#pragma unroll
      for (int mf = 0; mf < 4; mf++)
#pragma unroll
        for (int nf = 0; nf < 4; nf++) {
          acc[mf][nf] = MFMA16(ah[mf], bh[nf], acc[mf][nf]);
          acc[mf][nf] = MFMA16(ah[mf], bl[nf], acc[mf][nf]);
          acc[mf][nf] = MFMA16(al[mf], bh[nf], acc[mf][nf]);
        }
    }
    __syncthreads();
  }
  unsigned short* oc = (unsigned short*)outp;
#pragma unroll
  for (int nf = 0; nf < 4; nf++) {
    const int col = n0 + wn * 64 + nf * 16 + ln;
    const float bv = bias[col];
#pragma unroll
    for (int mf = 0; mf < 4; mf++)
#pragma unroll
      for (int r = 0; r < 4; r++) {
        const int row = m0 + wm * 64 + mf * 16 + g * 4 + r;
        float v = acc[mf][nf][r] + bv;
        v = v > 0.f ? v : 0.f;
        unsigned short h = f2bf(v);
        oc[(size_t)row * 2048 + col] = h;
        oc[(size_t)row * 2048 + 1024 + col] = f2bf(v - bf2f(h));
      }
  }
}

// ================= Tier A: score GEMM + masked softmax (R4: pipelined) =========
// grid (16,32) = 512 blocks, 512 thr = 8 waves (2 wm x 4 wn). S[64][1024] in regs.
// K double-buffered in LDS with prefetch-before-compute; q-frags in registers.
__global__ __launch_bounds__(512, 2) void k_attn2(const unsigned short* __restrict__ Khi,
                                                  const unsigned short* __restrict__ Klo,
                                                  const float* __restrict__ mask,
                                                  float* __restrict__ dout) {
  __shared__ __align__(16) unsigned short kbuf[2][2][128 * 64];  // [buf][plane][...]
  __shared__ float mask_s[1024];
  __shared__ float red[4][64];
  const int t = threadIdx.x;
  const int i = blockIdx.y * 16 + blockIdx.x;
  const int x = i & 7, jj = i >> 3;
  const int b = x * 4 + (jj >> 4), qt = jj & 15;
  const int q0 = qt * 64;
  const int w = t >> 6, l = t & 63, wm = w >> 2, wn = w & 3, g = l >> 4, ln = l & 15;
  const int lrow = l >> 3, lc8 = (l & 7) * 8, sc = lc8 ^ (lrow << 3);
  for (int ii = t; ii < 1024; ii += 512) mask_s[ii] = mask[b * 1024 + ii];
  const f32x4 fz = {0.f, 0.f, 0.f, 0.f};
  f32x4 acc[8][2][2];
#pragma unroll
  for (int kt = 0; kt < 8; kt++)
#pragma unroll
    for (int mf = 0; mf < 2; mf++)
#pragma unroll
      for (int nf = 0; nf < 2; nf++) acc[kt][mf][nf] = fz;
  const unsigned short* dou16 = (const unsigned short*)dout;
  const size_t kbase = (size_t)b * 1024 * 1024;

  // stage one 128x64 K tile (hi+lo) into kbuf[buf]; 2 chunks/wave/plane
  auto stageK = [&](int buf, int kt, int dc) {
#pragma unroll
    for (int jj2 = 0; jj2 < 2; jj2++) {
      const int ch = w * 2 + jj2;
      const int row = ch * 8 + lrow;
      const size_t go = kbase + (size_t)(kt * 128 + row) * 1024 + dc * 64 + sc;
      gld16(Khi + go, &kbuf[buf][0][ch * 512]);
      gld16(Klo + go, &kbuf[buf][1][ch * 512]);
    }
  };

  stageK(0, 0, 0);
  __syncthreads();
  int cur = 0;
#pragma unroll 1
  for (int dc = 0; dc < 16; dc++) {
    // q-fragments for this dc: straight global->VGPR (A-frag layout: row=ln, k=g*8)
    s16x8 qh[2][2], ql[2][2];  // [mf][ks]
#pragma unroll
    for (int mf = 0; mf < 2; mf++)
#pragma unroll
      for (int ks = 0; ks < 2; ks++) {
        const size_t rowoff = (size_t)(b * 1024 + q0 + wm * 32 + mf * 16 + ln) * 2048;
        const int col = dc * 64 + ks * 32 + g * 8;
        qh[mf][ks] = *(const s16x8*)(dou16 + rowoff + col);
        ql[mf][ks] = *(const s16x8*)(dou16 + rowoff + 1024 + col);
      }
#pragma unroll  // full: acc[kt] must be statically indexed (rule #20)
    for (int kt = 0; kt < 8; kt++) {
      // prefetch next tile into the other buffer (overlaps with compute below)
      if (!(dc == 15 && kt == 7)) {
        const int nkt = (kt + 1) & 7;
        const int ndc = (kt == 7) ? dc + 1 : dc;
        stageK(cur ^ 1, nkt, ndc);
      }
#pragma unroll
      for (int ks = 0; ks < 2; ks++) {
        const int kc = ks * 32 + g * 8;
        s16x8 bh[2], bl[2];
#pragma unroll
        for (int nf = 0; nf < 2; nf++) {
          const int row = wn * 32 + nf * 16 + ln;
          const int idx = row * 64 + (kc ^ ((row & 7) << 3));
          bh[nf] = *(const s16x8*)&kbuf[cur][0][idx];
          bl[nf] = *(const s16x8*)&kbuf[cur][1][idx];
        }
#pragma unroll
        for (int mf = 0; mf < 2; mf++)
#pragma unroll
          for (int nf = 0; nf < 2; nf++) {
            acc[kt][mf][nf] = MFMA16(qh[mf][ks], bh[nf], acc[kt][mf][nf]);
            acc[kt][mf][nf] = MFMA16(qh[mf][ks], bl[nf], acc[kt][mf][nf]);
            acc[kt][mf][nf] = MFMA16(ql[mf][ks], bh[nf], acc[kt][mf][nf]);
          }
      }
      __syncthreads();  // drains prefetch (vmcnt0) + all waves done reading cur
      cur ^= 1;
    }
  }
  // ---- masked softmax ----
  float rmax[2][4];
#pragma unroll
  for (int mf = 0; mf < 2; mf++)
#pragma unroll
    for (int r = 0; r < 4; r++) rmax[mf][r] = -1e30f;
#pragma unroll
  for (int kt = 0; kt < 8; kt++)
#pragma unroll
    for (int nf = 0; nf < 2; nf++) {
      const int k = kt * 128 + wn * 32 + nf * 16 + ln;
      const bool mk = mask_s[k] != 0.f;
#pragma unroll
      for (int mf = 0; mf < 2; mf++)
#pragma unroll
        for (int r = 0; r < 4; r++)
          if (mk) rmax[mf][r] = fmaxf(rmax[mf][r], acc[kt][mf][nf][r]);
    }
#pragma unroll
  for (int off = 1; off < 16; off <<= 1)
#pragma unroll
    for (int mf = 0; mf < 2; mf++)
#pragma unroll
      for (int r = 0; r < 4; r++) rmax[mf][r] = fmaxf(rmax[mf][r], __shfl_xor(rmax[mf][r], off));
  if (ln == 0) {
#pragma unroll
    for (int mf = 0; mf < 2; mf++)
#pragma unroll
      for (int r = 0; r < 4; r++) red[wn][wm * 32 + mf * 16 + g * 4 + r] = rmax[mf][r];
  }
  __syncthreads();
#pragma unroll
  for (int mf = 0; mf < 2; mf++)
#pragma unroll
    for (int r = 0; r < 4; r++) {
      const int row = wm * 32 + mf * 16 + g * 4 + r;
      rmax[mf][r] = fmaxf(fmaxf(red[0][row], red[1][row]), fmaxf(red[2][row], red[3][row]));
    }
  __syncthreads();
  float rsum[2][4];
#pragma unroll
  for (int mf = 0; mf < 2; mf++)
#pragma unroll
    for (int r = 0; r < 4; r++) rsum[mf][r] = 0.f;
#pragma unroll
  for (int kt = 0; kt < 8; kt++)
#pragma unroll
    for (int nf = 0; nf < 2; nf++) {
      const int k = kt * 128 + wn * 32 + nf * 16 + ln;
      const bool mk = mask_s[k] != 0.f;
#pragma unroll
      for (int mf = 0; mf < 2; mf++)
#pragma unroll
        for (int r = 0; r < 4; r++)
          if (mk) rsum[mf][r] += __expf(acc[kt][mf][nf][r] - rmax[mf][r]);
    }
#pragma unroll
  for (int off = 1; off < 16; off <<= 1)
#pragma unroll
    for (int mf = 0; mf < 2; mf++)
#pragma unroll
      for (int r = 0; r < 4; r++) rsum[mf][r] += __shfl_xor(rsum[mf][r], off);
  if (ln == 0) {
#pragma unroll
    for (int mf = 0; mf < 2; mf++)
#pragma unroll
      for (int r = 0; r < 4; r++) red[wn][wm * 32 + mf * 16 + g * 4 + r] = rsum[mf][r];
  }
  __syncthreads();
  float rinv[2][4];
#pragma unroll
  for (int mf = 0; mf < 2; mf++)
#pragma unroll
    for (int r = 0; r < 4; r++) {
      const int row = wm * 32 + mf * 16 + g * 4 + r;
      rinv[mf][r] = 1.f / (red[0][row] + red[1][row] + red[2][row] + red[3][row]);
    }
  unsigned short* oc = (unsigned short*)dout;
#pragma unroll
  for (int kt = 0; kt < 8; kt++)
#pragma unroll
    for (int nf = 0; nf < 2; nf++) {
      const int k = kt * 128 + wn * 32 + nf * 16 + ln;
      const bool mk = mask_s[k] != 0.f;
#pragma unroll
      for (int mf = 0; mf < 2; mf++)
#pragma unroll
        for (int r = 0; r < 4; r++) {
          const int q = q0 + wm * 32 + mf * 16 + g * 4 + r;
          float p = mk ? __expf(acc[kt][mf][nf][r] - rmax[mf][r]) * rinv[mf][r] : 0.f;
          oc[(size_t)(b * 1024 + q) * 2048 + 1024 + k] = f2bf(p);
        }
    }
}

// ================= Tier A: O = attn @ K via KhiT =================
// grid (8,32) = 256 blocks, 512 thr = 8 waves (2 wm x 4 wd). 128q x 512d, BK=64.
__global__ __launch_bounds__(512, 2) void k_pv2(const unsigned short* __restrict__ KhiT,
                                                float* __restrict__ dout, const int dh) {
  __shared__ __align__(16) unsigned short P[128 * 64];
  __shared__ __align__(16) unsigned short KT[512 * 64];
  const int t = threadIdx.x;
  const int i = blockIdx.y * 8 + blockIdx.x;
  const int x = i & 7, jj = i >> 3;
  const int b = x * 4 + (jj >> 3), qt = jj & 7;
  const int q0 = qt * 128, d0 = dh * 512;
  const int w = t >> 6, l = t & 63, wm = w >> 2, wd = w & 3, g = l >> 4, ln = l & 15;
  const int lrow = l >> 3, lc8 = (l & 7) * 8, sc = lc8 ^ (lrow << 3);
  const f32x4 fz = {0.f, 0.f, 0.f, 0.f};
  f32x4 acc[4][8];
#pragma unroll
  for (int a = 0; a < 4; a++)
#pragma unroll
    for (int bq = 0; bq < 8; bq++) acc[a][bq] = fz;
  const unsigned short* dou16 = (const unsigned short*)dout;
  const size_t kbase = (size_t)b * 1024 * 1024;
#pragma unroll 1
  for (int k0 = 0; k0 < 1024; k0 += 64) {
#pragma unroll
    for (int jj2 = 0; jj2 < 2; jj2++) {  // P: 16 chunks
      const int ch = w * 2 + jj2;
      const int row = ch * 8 + lrow;
      gld16(dou16 + (size_t)(b * 1024 + q0 + row) * 2048 + 1024 + k0 + sc, &P[ch * 512]);
    }
#pragma unroll
    for (int jj2 = 0; jj2 < 8; jj2++) {  // KT: 64 chunks
      const int ch = w * 8 + jj2;
      const int row = ch * 8 + lrow;
      gld16(KhiT + kbase + (size_t)(d0 + row) * 1024 + k0 + sc, &KT[ch * 512]);
    }
    __syncthreads();
#pragma unroll
    for (int ks = 0; ks < 2; ks++) {
      const int kc = ks * 32 + g * 8;
      s16x8 a[4], bb[8];
#pragma unroll
      for (int mf = 0; mf < 4; mf++) {
        const int row = wm * 64 + mf * 16 + ln;
        a[mf] = *(const s16x8*)&P[row * 64 + (kc ^ ((row & 7) << 3))];
      }
#pragma unroll
      for (int nf = 0; nf < 8; nf++) {
        const int row = wd * 128 + nf * 16 + ln;
        bb[nf] = *(const s16x8*)&KT[row * 64 + (kc ^ ((row & 7) << 3))];
      }
#pragma unroll
      for (int mf = 0; mf < 4; mf++)
#pragma unroll
        for (int nf = 0; nf < 8; nf++) acc[mf][nf] = MFMA16(a[mf], bb[nf], acc[mf][nf]);
    }
    __syncthreads();
  }
#pragma unroll
  for (int mf = 0; mf < 4; mf++)
#pragma unroll
    for (int nf = 0; nf < 8; nf++)
#pragma unroll
      for (int r = 0; r < 4; r++) {
        const int q = q0 + wm * 64 + mf * 16 + g * 4 + r;
        const int d = d0 + wd * 128 + nf * 16 + ln;
        dout[(size_t)(b * 1024 + q) * 1024 + d] = acc[mf][nf][r];
      }
}

// ================= Tier B/C: round-1 kernels (fallback) =================
__global__ __launch_bounds__(256, 2) void k_qf(const float* __restrict__ Q,
                                               const float* __restrict__ W,
                                               const float* __restrict__ bias,
                                               float* __restrict__ qf, const int packout) {
  __shared__ __align__(16) short Ah[128 * 64], Al[128 * 64], Bh[128 * 64], Bl[128 * 64];
  const int t = threadIdx.x;
  const int m0 = blockIdx.x * 128, n0 = blockIdx.y * 128;
  const int w = t >> 6, l = t & 63, wm = w >> 1, wn = w & 1, g = l >> 4, ln = l & 15;
  const f32x4 fz = {0.f, 0.f, 0.f, 0.f};
  f32x4 acc[4][4];
#pragma unroll
  for (int a = 0; a < 4; a++)
#pragma unroll
    for (int bq = 0; bq < 4; bq++) acc[a][bq] = fz;
  const int srow = t >> 1, scol = (t & 1) * 32;
#pragma unroll 1
  for (int k0 = 0; k0 < 1024; k0 += 64) {
    const float* sa = Q + (size_t)(m0 + srow) * 1024 + k0 + scol;
    const float* sb = W + (size_t)(n0 + srow) * 1024 + k0 + scol;
#pragma unroll
    for (int c = 0; c < 32; c += 8) {
      s16x8 h, lo;
      cvt8(sa + c, h, lo);
      int si = swz(srow, scol + c);
      *(s16x8*)&Ah[si] = h;
      *(s16x8*)&Al[si] = lo;
    }
#pragma unroll
    for (int c = 0; c < 32; c += 8) {
      s16x8 h, lo;
      cvt8(sb + c, h, lo);
      int si = swz(srow, scol + c);
      *(s16x8*)&Bh[si] = h;
      *(s16x8*)&Bl[si] = lo;
    }
    __syncthreads();
#pragma unroll
    for (int ks = 0; ks < 2; ks++) {
      const int kc = ks * 32 + g * 8;
      s16x8 ah[4], al[4], bh[4], bl[4];
#pragma unroll
      for (int mf = 0; mf < 4; mf++) {
        int si = swz(wm * 64 + mf * 16 + ln, kc);
        ah[mf] = *(s16x8*)&Ah[si];
        al[mf] = *(s16x8*)&Al[si];
      }
#pragma unroll
      for (int nf = 0; nf < 4; nf++) {
        int si = swz(wn * 64 + nf * 16 + ln, kc);
        bh[nf] = *(s16x8*)&Bh[si];
        bl[nf] = *(s16x8*)&Bl[si];
      }
#pragma unroll
      for (int mf = 0; mf < 4; mf++)
#pragma unroll
        for (int nf = 0; nf < 4; nf++) {
          acc[mf][nf] = MFMA16(ah[mf], bh[nf], acc[mf][nf]);
          acc[mf][nf] = MFMA16(ah[mf], bl[nf], acc[mf][nf]);
          acc[mf][nf] = MFMA16(al[mf], bh[nf], acc[mf][nf]);
        }
    }
    __syncthreads();
  }
  unsigned short* oc = (unsigned short*)qf;
#pragma unroll
  for (int nf = 0; nf < 4; nf++) {
    const int col = n0 + wn * 64 + nf * 16 + ln;
    const float bv = bias[col];
#pragma unroll
    for (int mf = 0; mf < 4; mf++)
#pragma unroll
      for (int r = 0; r < 4; r++) {
        const int row = m0 + wm * 64 + mf * 16 + g * 4 + r;
        float v = acc[mf][nf][r] + bv;
        v = v > 0.f ? v : 0.f;
        if (packout) {
          unsigned short h = f2bf(v);
          oc[(size_t)row * 2048 + col] = h;
          oc[(size_t)row * 2048 + 1024 + col] = f2bf(v - bf2f(h));
        } else {
          qf[(size_t)row * 1024 + col] = v;
        }
      }
  }
}

__global__ __launch_bounds__(512, 2) void k_attn(const float* __restrict__ Key,
                                                 const float* __restrict__ mask,
                                                 float* __restrict__ dout) {
  __shared__ __align__(16) short qh[64 * 64], qlo[64 * 64], kh[128 * 64], klo[128 * 64];
  __shared__ float mask_s[1024];
  __shared__ float red[4][64];
  const int t = threadIdx.x;
  const int qt = blockIdx.x, b = blockIdx.y;
  const int q0 = qt * 64;
  const int w = t >> 6, l = t & 63, wm = w >> 2, wn = w & 3, g = l >> 4, ln = l & 15;
  for (int i = t; i < 1024; i += 512) mask_s[i] = mask[b * 1024 + i];
  const f32x4 fz = {0.f, 0.f, 0.f, 0.f};
  f32x4 acc[8][2][2];
#pragma unroll
  for (int kt = 0; kt < 8; kt++)
#pragma unroll
    for (int mf = 0; mf < 2; mf++)
#pragma unroll
      for (int nf = 0; nf < 2; nf++) acc[kt][mf][nf] = fz;
  const float* qfb = dout + (size_t)(b * 1024 + q0) * 1024;
  const float* kb = Key + (size_t)b * 1024 * 1024;
  const int qrow = t >> 3, qcol = (t & 7) * 8;
  const int krow = t >> 2, kcol0 = (t & 3) * 16;
#pragma unroll 1
  for (int dc = 0; dc < 16; dc++) {
    {
      s16x8 h, lo;
      cvt8(qfb + (size_t)qrow * 1024 + dc * 64 + qcol, h, lo);
      int si = swz(qrow, qcol);
      *(s16x8*)&qh[si] = h;
      *(s16x8*)&qlo[si] = lo;
    }
#pragma unroll
    for (int kt = 0; kt < 8; kt++) {
      {
        const float* s = kb + (size_t)(kt * 128 + krow) * 1024 + dc * 64 + kcol0;
        s16x8 h, lo;
        cvt8(s, h, lo);
        int si = swz(krow, kcol0);
        *(s16x8*)&kh[si] = h;
        *(s16x8*)&klo[si] = lo;
        cvt8(s + 8, h, lo);
        si = swz(krow, kcol0 + 8);
        *(s16x8*)&kh[si] = h;
        *(s16x8*)&klo[si] = lo;
      }
      __syncthreads();
#pragma unroll
      for (int ks = 0; ks < 2; ks++) {
        const int kc = ks * 32 + g * 8;
        s16x8 ah[2], al2[2], bh[2], bl[2];
#pragma unroll
        for (int mf = 0; mf < 2; mf++) {
          int si = swz(wm * 32 + mf * 16 + ln, kc);
          ah[mf] = *(s16x8*)&qh[si];
          al2[mf] = *(s16x8*)&qlo[si];
        }
#pragma unroll
        for (int nf = 0; nf < 2; nf++) {
          int si = swz(wn * 32 + nf * 16 + ln, kc);
          bh[nf] = *(s16x8*)&kh[si];
          bl[nf] = *(s16x8*)&klo[si];
        }
#pragma unroll
        for (int mf = 0; mf < 2; mf++)
#pragma unroll
          for (int nf = 0; nf < 2; nf++) {
            acc[kt][mf][nf] = MFMA16(ah[mf], bh[nf], acc[kt][mf][nf]);
            acc[kt][mf][nf] = MFMA16(ah[mf], bl[nf], acc[kt][mf][nf]);
            acc[kt][mf][nf] = MFMA16(al2[mf], bh[nf], acc[kt][mf][nf]);
          }
      }
      __syncthreads();
    }
  }
  float rmax[2][4];
#pragma unroll
  for (int mf = 0; mf < 2; mf++)
#pragma unroll
    for (int r = 0; r < 4; r++) rmax[mf][r] = -1e30f;
#pragma unroll
  for (int kt = 0; kt < 8; kt++)
#pragma unroll
    for (int nf = 0; nf < 2; nf++) {
      const int k = kt * 128 + wn * 32 + nf * 16 + ln;
      const bool mk = mask_s[k] != 0.f;
#pragma unroll
      for (int mf = 0; mf < 2; mf++)
#pragma unroll
        for (int r = 0; r < 4; r++)
          if (mk) rmax[mf][r] = fmaxf(rmax[mf][r], acc[kt][mf][nf][r]);
    }
#pragma unroll
  for (int off = 1; off < 16; off <<= 1)
#pragma unroll
    for (int mf = 0; mf < 2; mf++)
#pragma unroll
      for (int r = 0; r < 4; r++) rmax[mf][r] = fmaxf(rmax[mf][r], __shfl_xor(rmax[mf][r], off));
  if (ln == 0) {
#pragma unroll
    for (int mf = 0; mf < 2; mf++)
#pragma unroll
      for (int r = 0; r < 4; r++) red[wn][wm * 32 + mf * 16 + g * 4 + r] = rmax[mf][r];
  }
  __syncthreads();
#pragma unroll
  for (int mf = 0; mf < 2; mf++)
#pragma unroll
    for (int r = 0; r < 4; r++) {
      const int row = wm * 32 + mf * 16 + g * 4 + r;
      rmax[mf][r] = fmaxf(fmaxf(red[0][row], red[1][row]), fmaxf(red[2][row], red[3][row]));
    }
  __syncthreads();
  float rsum[2][4];
#pragma unroll
  for (int mf = 0; mf < 2; mf++)
#pragma unroll
    for (int r = 0; r < 4; r++) rsum[mf][r] = 0.f;
#pragma unroll
  for (int kt = 0; kt < 8; kt++)
#pragma unroll
    for (int nf = 0; nf < 2; nf++) {
      const int k = kt * 128 + wn * 32 + nf * 16 + ln;
      const bool mk = mask_s[k] != 0.f;
#pragma unroll
      for (int mf = 0; mf < 2; mf++)
#pragma unroll
        for (int r = 0; r < 4; r++)
          if (mk) rsum[mf][r] += __expf(acc[kt][mf][nf][r] - rmax[mf][r]);
    }
#pragma unroll
  for (int off = 1; off < 16; off <<= 1)
#pragma unroll
    for (int mf = 0; mf < 2; mf++)
#pragma unroll
      for (int r = 0; r < 4; r++) rsum[mf][r] += __shfl_xor(rsum[mf][r], off);
  if (ln == 0) {
#pragma unroll
    for (int mf = 0; mf < 2; mf++)
#pragma unroll
      for (int r = 0; r < 4; r++) red[wn][wm * 32 + mf * 16 + g * 4 + r] = rsum[mf][r];
  }
  __syncthreads();
  float rinv[2][4];
#pragma unroll
  for (int mf = 0; mf < 2; mf++)
#pragma unroll
    for (int r = 0; r < 4; r++) {
      const int row = wm * 32 + mf * 16 + g * 4 + r;
      rinv[mf][r] = 1.f / (red[0][row] + red[1][row] + red[2][row] + red[3][row]);
    }
  char* oc = (char*)dout;
#pragma unroll
  for (int kt = 0; kt < 8; kt++)
#pragma unroll
    for (int nf = 0; nf < 2; nf++) {
      const int k = kt * 128 + wn * 32 + nf * 16 + ln;
      const bool mk = mask_s[k] != 0.f;
#pragma unroll
      for (int mf = 0; mf < 2; mf++)
#pragma unroll
        for (int r = 0; r < 4; r++) {
          const int q = q0 + wm * 32 + mf * 16 + g * 4 + r;
          float p = mk ? __expf(acc[kt][mf][nf][r] - rmax[mf][r]) * rinv[mf][r] : 0.f;
          *(unsigned short*)(oc + (size_t)(b * 1024 + q) * 4096 + 2048 + k * 2) = f2bf(p);
        }
    }
}

__global__ __launch_bounds__(512, 2) void k_pv(const float* __restrict__ Key,
                                               float* __restrict__ dout, const int dh) {
  __shared__ __align__(16) short P[128 * 64];
  __shared__ __align__(16) short KT[512 * 64];
  const int t = threadIdx.x;
  const int qt = blockIdx.x, b = blockIdx.y;
  const int q0 = qt * 128, d0 = dh * 512;
  const int w = t >> 6, l = t & 63, wm = w >> 2, wd = w & 3, g = l >> 4, ln = l & 15;
  const f32x4 fz = {0.f, 0.f, 0.f, 0.f};
  f32x4 acc[4][8];
#pragma unroll
  for (int a = 0; a < 4; a++)
#pragma unroll
    for (int bq = 0; bq < 8; bq++) acc[a][bq] = fz;
  const char* ab = (const char*)dout;
  const int prow = t >> 2, pc0 = (t & 3) * 16;
#pragma unroll 1
  for (int k0 = 0; k0 < 1024; k0 += 64) {
    {
      const unsigned short* s =
          (const unsigned short*)(ab + (size_t)(b * 1024 + q0 + prow) * 4096 + 2048) + k0 + pc0;
      s16x8 p0 = *(const s16x8*)s, p1 = *(const s16x8*)(s + 8);
      *(s16x8*)&P[swz(prow, pc0)] = p0;
      *(s16x8*)&P[swz(prow, pc0 + 8)] = p1;
    }
    {
      const float* ksrc = Key + (size_t)b * 1024 * 1024 + (size_t)k0 * 1024 + d0 + t;
#pragma unroll
      for (int kg = 0; kg < 8; kg++) {
        s16x8 h;
#pragma unroll
        for (int jx = 0; jx < 8; jx++) h[jx] = (short)f2bf(ksrc[(size_t)(kg * 8 + jx) * 1024]);
        *(s16x8*)&KT[swz(t, kg * 8)] = h;
      }
    }
    __syncthreads();
#pragma unroll
    for (int ks = 0; ks < 2; ks++) {
      const int kc = ks * 32 + g * 8;
      s16x8 a[4], bb[8];
#pragma unroll
      for (int mf = 0; mf < 4; mf++) a[mf] = *(s16x8*)&P[swz(wm * 64 + mf * 16 + ln, kc)];
#pragma unroll
      for (int nf = 0; nf < 8; nf++) bb[nf] = *(s16x8*)&KT[swz(wd * 128 + nf * 16 + ln, kc)];
#pragma unroll
      for (int mf = 0; mf < 4; mf++)
#pragma unroll
        for (int nf = 0; nf < 8; nf++) acc[mf][nf] = MFMA16(a[mf], bb[nf], acc[mf][nf]);
    }
    __syncthreads();
  }
#pragma unroll
  for (int mf = 0; mf < 4; mf++)
#pragma unroll
    for (int nf = 0; nf < 8; nf++)
#pragma unroll
      for (int r = 0; r < 4; r++) {
        const int q = q0 + wm * 64 + mf * 16 + g * 4 + r;
        const int d = d0 + wd * 128 + nf * 16 + ln;
        dout[(size_t)(b * 1024 + q) * 1024 + d] = acc[mf][nf][r];
      }
}

extern "C" void kernel_launch(void* const* d_in, const int* in_sizes, int n_in,
                              void* d_out, int out_size, void* d_ws, size_t ws_size,
                              hipStream_t stream) {
  const float* Q = (const float*)d_in[0];
  const float* K = (const float*)d_in[1];
  const float* M = (const float*)d_in[2];
  const float* W = (const float*)d_in[3];
  const float* bias = (const float*)d_in[4];
  float* out = (float*)d_out;
  char* wsb = (char*)d_ws;
  (void)in_sizes; (void)n_in; (void)out_size;

  const bool tierA = ws_size >= WS_TIER_A;
  const bool tierB2 = !tierA && ws_size >= WS_TIER_B2;
  if (tierA || tierB2) {
    unsigned short* Khi = (unsigned short*)(wsb + OFF_KHI);
    unsigned short* Klo = (unsigned short*)(wsb + OFF_KLO);
    unsigned short* KhiT = (unsigned short*)(wsb + OFF_KHIT);
    k_cvt_k<<<dim3(16, 16, 32), 256, 0, stream>>>(K, Khi, Klo, KhiT);
    if (tierA) {
      unsigned short* Qhi = (unsigned short*)(wsb + OFF_QHI);
      unsigned short* Qlo = (unsigned short*)(wsb + OFF_QLO);
      unsigned short* Whi = (unsigned short*)(wsb + OFF_WHI);
      unsigned short* Wlo = (unsigned short*)(wsb + OFF_WLO);
      k_cvt_pair<<<16384, 256, 0, stream>>>(Q, Qhi, Qlo, 4194304);
      k_cvt_pair<<<512, 256, 0, stream>>>(W, Whi, Wlo, 131072);
      k_qf2<<<dim3(256, 8), 256, 0, stream>>>(Qhi, Qlo, Whi, Wlo, bias, out);
    } else {
      k_qf<<<dim3(256, 8), 256, 0, stream>>>(Q, W, bias, out, 1);
    }
    k_attn2<<<dim3(16, 32), 512, 0, stream>>>(Khi, Klo, M, out);
    k_pv2<<<dim3(8, 32), 512, 0, stream>>>(KhiT, out, 0);
    k_pv2<<<dim3(8, 32), 512, 0, stream>>>(KhiT, out, 1);
  } else {
    k_qf<<<dim3(256, 8), 256, 0, stream>>>(Q, W, bias, out, 0);
    k_attn<<<dim3(16, 32), 512, 0, stream>>>(K, M, out);
    k_pv<<<dim3(8, 32), 512, 0, stream>>>(K, out, 0);
    k_pv<<<dim3(8, 32), 512, 0, stream>>>(K, out, 1);
  }
}